// Round 11
// baseline (1087.325 us; speedup 1.0000x reference)
//
#include <hip/hip_runtime.h>
#include <hip/hip_bf16.h>

#define BB 8
#define NN 4096
#define DD 64
#define SS 1024
#define KK 32
#define C1 64
#define C2 128

typedef unsigned int uint32;
typedef unsigned long long uint64;

constexpr int BSK = BB * SS * KK;   // 262144
constexpr int BS  = BB * SS;        // 8192

// ---- per-slot stats offsets (slot stride = 704 floats, 64 slots) ----
#define ST_S1_C1 0
#define ST_S2_C1 64
#define ST_S1_C2 128
#define ST_S2_C2 256
#define ST_S1_W0 384
#define ST_S2_W0 392
#define ST_S1_W1 400
#define ST_S2_W1 408
#define ST_S1_W2 416
#define ST_S2_W2 432
#define ST_S1_Y  448
#define ST_S2_Y  576
#define ST_STRIDE 704
#define N_SLOTS 64

#define PA_A_C1 0
#define PA_C_C1 64
#define PA_A_C2 128
#define PA_C_C2 256
#define PA_A_W0 384
#define PA_C_W0 392
#define PA_A_W1 400
#define PA_C_W1 408
#define PA_A_W2 416
#define PA_C_W2 432
// params floats [448, 704) are unused -> progress counters live there

// ------------------------------------------------------------------
// DPP cross-lane helpers (packed-key trick, see prior session notes)
// ------------------------------------------------------------------
#if __has_builtin(__builtin_amdgcn_update_dpp)
#define HAS_DPP 1
template <int CTRL>
__device__ __forceinline__ double dpp_f64(double x) {
    uint64 u = (uint64)__double_as_longlong(x);
    int lo = (int)(uint32)u, hi = (int)(uint32)(u >> 32);
    int lo2 = __builtin_amdgcn_update_dpp(lo, lo, CTRL, 0xf, 0xf, false);
    int hi2 = __builtin_amdgcn_update_dpp(hi, hi, CTRL, 0xf, 0xf, false);
    return __longlong_as_double((long long)(((uint64)(uint32)hi2 << 32) | (uint32)lo2));
}
__device__ __forceinline__ double wave_max_pack(double k) {
    k = fmax(k, dpp_f64<0x111>(k));
    k = fmax(k, dpp_f64<0x112>(k));
    k = fmax(k, dpp_f64<0x114>(k));
    k = fmax(k, dpp_f64<0x118>(k));
    k = fmax(k, dpp_f64<0x142>(k));
    k = fmax(k, dpp_f64<0x143>(k));
    return k;                          // lane 63 holds wave max
}
__device__ __forceinline__ double wave_min_pack(double k) {
    k = fmin(k, dpp_f64<0x111>(k));
    k = fmin(k, dpp_f64<0x112>(k));
    k = fmin(k, dpp_f64<0x114>(k));
    k = fmin(k, dpp_f64<0x118>(k));
    k = fmin(k, dpp_f64<0x142>(k));
    k = fmin(k, dpp_f64<0x143>(k));
    return k;                          // lane 63 holds wave min
}
__device__ __forceinline__ uint64 bcast63_u64(double k) {
#if __has_builtin(__builtin_amdgcn_readlane)
    uint64 u = (uint64)__double_as_longlong(k);
    int lo = __builtin_amdgcn_readlane((int)(uint32)u, 63);
    int hi = __builtin_amdgcn_readlane((int)(uint32)(u >> 32), 63);
    return ((uint64)(uint32)hi << 32) | (uint32)lo;
#else
    return (uint64)__double_as_longlong(__shfl(k, 63));
#endif
}
#define FPS_WRITER_LANE 63
template <int CTRL>
__device__ __forceinline__ float dpp_mov_f32(float x) {
    int r = __builtin_amdgcn_update_dpp(__float_as_int(x), __float_as_int(x),
                                        CTRL, 0xf, 0xf, false);
    return __int_as_float(r);
}
__device__ __forceinline__ float wave_sum_f32(float v) {
    v += dpp_mov_f32<0x111>(v);
    v += dpp_mov_f32<0x112>(v);
    v += dpp_mov_f32<0x114>(v);
    v += dpp_mov_f32<0x118>(v);
    v += dpp_mov_f32<0x142>(v);
    v += dpp_mov_f32<0x143>(v);
    return v;                          // lane 63 holds wave sum
}
#define LIN_WRITER 63
#else
#define HAS_DPP 0
__device__ __forceinline__ double wave_max_pack(double k) {
#pragma unroll
    for (int m = 32; m >= 1; m >>= 1) k = fmax(k, __shfl_xor(k, m));
    return k;
}
__device__ __forceinline__ double wave_min_pack(double k) {
#pragma unroll
    for (int m = 32; m >= 1; m >>= 1) k = fmin(k, __shfl_xor(k, m));
    return k;
}
__device__ __forceinline__ uint64 bcast63_u64(double k) {
    return (uint64)__double_as_longlong(k);
}
#define FPS_WRITER_LANE 0
__device__ __forceinline__ float wave_sum_f32(float v) {
#pragma unroll
    for (int m = 32; m >= 1; m >>= 1) v += __shfl_xor(v, m);
    return v;
}
#define LIN_WRITER 0
#endif

// exact RNE f32 -> bf16 bits
__device__ __forceinline__ uint32 bf16rne(float x) {
    uint32 u = __float_as_uint(x);
    return (u + 0x7fffu + ((u >> 16) & 1u)) >> 16;
}

// MFMA fragment types (guide-blessed)
typedef __attribute__((ext_vector_type(8))) short bf16x8;
typedef __attribute__((ext_vector_type(4))) float f32x4v;

// ------------------------------------------------------------------
// staging: gather 32 neighbors x 64 dims (bf16 -> fp32 LDS)
// ------------------------------------------------------------------
__device__ __forceinline__ void stage_pts(const __hip_bfloat16* __restrict__ ptsT,
                                          const int* __restrict__ nidx,
                                          int q, int b, int t, float* pts) {
    int k = t >> 3, d8 = t & 7;
    int nn = nidx[(size_t)q * KK + k];
    uint4 u = ((const uint4*)ptsT)[((size_t)b * NN + nn) * 8 + d8];
    float4 lo, hi;
    lo.x = __uint_as_float(u.x << 16); lo.y = __uint_as_float(u.x & 0xffff0000u);
    lo.z = __uint_as_float(u.y << 16); lo.w = __uint_as_float(u.y & 0xffff0000u);
    hi.x = __uint_as_float(u.z << 16); hi.y = __uint_as_float(u.z & 0xffff0000u);
    hi.z = __uint_as_float(u.w << 16); hi.w = __uint_as_float(u.w & 0xffff0000u);
    *(float4*)&pts[k * 64 + d8 * 8] = lo;
    *(float4*)&pts[k * 64 + d8 * 8 + 4] = hi;
}

// ------------------------------------------------------------------
// prep_fps_knn: blocks [0,8) FPS (streaming publish of new_xyz every
// 32 steps); [8,520) points transpose; [520,1592) weight transposes;
// [1592,3640) kNN consumers that acquire-poll progress and, when
// fuse_a==1, run the pass_a body (gather+conv1+f1pre+stats) for their
// 4 queries inside the FPS shadow. Short blocks release-increment
// progress[8]; consumers acquire-wait for all 1584 before touching
// ptsT/w1t (cross-XCD visibility). LDS padded to 82,048 B => exactly
// ONE block per CU (FPS blocks own their CUs; measured -63us in r10).
// ------------------------------------------------------------------
__global__ __launch_bounds__(256) void prep_fps_knn(const float* __restrict__ points,
                                                    __hip_bfloat16* __restrict__ ptsT,
                                                    const float* __restrict__ c1_w,
                                                    const float* __restrict__ c2_w,
                                                    const float* __restrict__ lin_w,
                                                    float* __restrict__ w1t,
                                                    float* __restrict__ w2t,
                                                    __hip_bfloat16* __restrict__ linB,
                                                    const float* __restrict__ xyz,
                                                    float* __restrict__ new_xyz,
                                                    float* __restrict__ out0,
                                                    int* __restrict__ progress,
                                                    int* __restrict__ nidx,
                                                    float* __restrict__ offs,
                                                    const float* __restrict__ c1_b,
                                                    const float* __restrict__ w0_w,
                                                    const float* __restrict__ w0_b,
                                                    float* __restrict__ stats,
                                                    float* __restrict__ f1pre,
                                                    int fuse_a) {
    __shared__ __align__(16) char smu[82048];   // >81,920 B => 1 block/CU
    int t = threadIdx.x;
    int blk = blockIdx.x;
    if (blk < 8) {
        // -------- FPS (exclusive CU) --------
        __builtin_amdgcn_s_setprio(3);
        float4* xyz4 = (float4*)smu;              // [NN] 65536 B
        int* hist = (int*)(smu + 65536);          // [SS] 4096 B
        double* slots = (double*)(smu + 69632);   // [2][4] 64 B
        int b = blk;
        int wv = t >> 6, lane = t & 63;
        const float* base = xyz + (size_t)b * 3 * NN;
        float px[16], py[16], pz[16], dl[16];
        uint32 lidx[16];
#pragma unroll
        for (int i = 0; i < 16; i++) {
            int n = t + 256 * i;
            px[i] = base[n];
            py[i] = base[NN + n];
            pz[i] = base[2 * NN + n];
            float4 v; v.x = px[i]; v.y = py[i]; v.z = pz[i]; v.w = 0.f;
            xyz4[n] = v;
            dl[i] = 1e10f;
            lidx[i] = (uint32)(NN - 1 - n);
        }
        if (t == 0) hist[0] = 0;
        __syncthreads();
        int far = 0;
        for (int step = 1; step < SS; step++) {
            int p = step & 1;
            float4 c = xyz4[far];                 // one b128 broadcast read
            float cx = c.x, cy = c.y, cz = c.z;
            double k0 = 0.0, k1 = 0.0, k2 = 0.0, k3 = 0.0;
#pragma unroll
            for (int i = 0; i < 16; i++) {
                // EXACT arithmetic (must match jax reference bit-for-bit)
                float dx = __fsub_rn(px[i], cx);
                float dy = __fsub_rn(py[i], cy);
                float dz = __fsub_rn(pz[i], cz);
                float d = __fadd_rn(__fadd_rn(__fmul_rn(dx, dx), __fmul_rn(dy, dy)),
                                    __fmul_rn(dz, dz));
                float nd = fminf(dl[i], d);
                dl[i] = nd;
                uint64 kbits = ((uint64)__float_as_uint(nd) << 32) | lidx[i];
                double kk = __longlong_as_double((long long)kbits);
                if ((i & 3) == 0) k0 = fmax(k0, kk);
                else if ((i & 3) == 1) k1 = fmax(k1, kk);
                else if ((i & 3) == 2) k2 = fmax(k2, kk);
                else k3 = fmax(k3, kk);
            }
            double kbest = fmax(fmax(k0, k1), fmax(k2, k3));
            kbest = wave_max_pack(kbest);
            if (lane == FPS_WRITER_LANE) slots[p * 4 + wv] = kbest;
            __syncthreads();
            double s0 = slots[p * 4 + 0], s1 = slots[p * 4 + 1];
            double s2 = slots[p * 4 + 2], s3 = slots[p * 4 + 3];
            double bk = fmax(fmax(s0, s1), fmax(s2, s3));
            uint64 kb = (uint64)__double_as_longlong(bk);
            int bbx = (NN - 1) - (int)(uint32)(kb & 0xffffffffull);
            far = bbx;
            if (t == 0) hist[step] = bbx;
            // streaming publish: every 32 steps, wave-0 lanes 0-31 push
            // entries [step-33, step-1) then lane 0 release-stores progress.
            if ((step & 31) == 1 && step > 32) {
                if (t < 32) {
                    int s2p = step - 33 + t;
                    int idx2 = hist[s2p];
                    float4 v2 = xyz4[idx2];
                    size_t qq = (size_t)(b * SS + s2p) * 3;
                    new_xyz[qq + 0] = v2.x;
                    new_xyz[qq + 1] = v2.y;
                    new_xyz[qq + 2] = v2.z;
                }
                if (t == 0)
                    __hip_atomic_store(&progress[b], step - 1, __ATOMIC_RELEASE,
                                       __HIP_MEMORY_SCOPE_AGENT);
            }
        }
        __syncthreads();
        // epilogue: coalesced output writes
        for (int s = t; s < SS; s += 256) {
            int idx = hist[s];
            float4 v = xyz4[idx];
            size_t q = (size_t)(b * SS + s);
            new_xyz[q * 3 + 0] = v.x;
            new_xyz[q * 3 + 1] = v.y;
            new_xyz[q * 3 + 2] = v.z;
            out0[(size_t)b * 3 * SS + 0 * SS + s] = v.x;
            out0[(size_t)b * 3 * SS + 1 * SS + s] = v.y;
            out0[(size_t)b * 3 * SS + 2 * SS + s] = v.z;
        }
        __threadfence();
        __syncthreads();
        if (t == 0)
            __hip_atomic_store(&progress[b], SS, __ATOMIC_RELEASE,
                               __HIP_MEMORY_SCOPE_AGENT);
        __builtin_amdgcn_s_setprio(0);
    } else if (blk < 520) {
        // -------- points transpose --------
        float (*tile)[65] = (float(*)[65])smu;
        int bb = blk - 8;
        int b = bb >> 6;
        int n0 = (bb & 63) * 64;
        for (int i = t; i < 4096; i += 256) {
            int d = i >> 6, n = i & 63;
            tile[d][n] = points[((size_t)b * DD + d) * NN + n0 + n];
        }
        __syncthreads();
        for (int i = t; i < 4096; i += 256) {
            int n = i >> 6, d = i & 63;
            ptsT[((size_t)b * NN + n0 + n) * DD + d] = __float2bfloat16(tile[d][n]);
        }
        __threadfence();
        __syncthreads();
        if (t == 0)
            __hip_atomic_fetch_add(&progress[8], 1, __ATOMIC_RELEASE,
                                   __HIP_MEMORY_SCOPE_AGENT);
    } else if (blk < 1592) {
        // -------- weight transposes + lin_w -> bf16 --------
        int i = (blk - 520) * 256 + t;
        if (i < 4096) {
            int d = i >> 6, c = i & 63;
            w1t[d * 64 + c] = c1_w[c * 64 + d];
        }
        int j = i - 4096;
        if (j >= 0 && j < 8192) {
            int d = j >> 7, c = j & 127;
            w2t[d * 128 + c] = c2_w[c * 64 + d];
        }
        int l = i - 12288;
        if (l >= 0 && l < 262144) linB[l] = __float2bfloat16(lin_w[l]);
        __threadfence();
        __syncthreads();
        if (t == 0)
            __hip_atomic_fetch_add(&progress[8], 1, __ATOMIC_RELEASE,
                                   __HIP_MEMORY_SCOPE_AGENT);
    } else {
        // -------- kNN consumer (+fused pass_a): interleaved map --------
        int cb = blk - 1592;                  // 0..2047
        int wv = t >> 6, lane = t & 63;
        int bq = cb & 7;                      // batch
        int p0 = (cb >> 3) << 2;              // position base (4/block)
        int pos = p0 + wv;                    // this wave's position
        int q = bq * SS + pos;                // global query
        int needed = pos + 1;
        while (__hip_atomic_load(&progress[bq], __ATOMIC_ACQUIRE,
                                 __HIP_MEMORY_SCOPE_AGENT) < needed)
            __builtin_amdgcn_s_sleep(32);
        const float* base = xyz + (size_t)bq * 3 * NN;
        {
            float sx = new_xyz[(size_t)q * 3 + 0];
            float sy = new_xyz[(size_t)q * 3 + 1];
            float sz = new_xyz[(size_t)q * 3 + 2];
            float s2 = __fadd_rn(__fadd_rn(__fmul_rn(sx, sx), __fmul_rn(sy, sy)),
                                 __fmul_rn(sz, sz));
            float dl[64];
#pragma unroll
            for (int i = 0; i < 64; i++) {
                int n = i * 64 + lane;
                float x = base[n], y = base[NN + n], z = base[2 * NN + n];
                float d2 = __fadd_rn(__fadd_rn(__fmul_rn(x, x), __fmul_rn(y, y)), __fmul_rn(z, z));
                float dot = __fadd_rn(__fadd_rn(__fmul_rn(sx, x), __fmul_rn(sy, y)), __fmul_rn(sz, z));
                float v = __fmul_rn(-2.0f, dot);
                v = __fadd_rn(v, s2);
                v = __fadd_rn(v, d2);
                dl[i] = v;
            }
            const float MASKF = __uint_as_float(0x7F7FFFFFu);   // FLT_MAX
            unsigned long long excl = 0ull;
            for (int k = 0; k < KK; k++) {
                float best = MASKF;
                int bslot = 0;
#pragma unroll
                for (int i = 0; i < 64; i++) {
                    bool ok = ((excl >> i) & 1ull) == 0ull;
                    float v = ok ? dl[i] : MASKF;
                    if (v < best) { best = v; bslot = i; }
                }
                uint64 kbits = ((uint64)__float_as_uint(best) << 32) |
                               (uint32)(bslot * 64 + lane);
                double kb = wave_min_pack(__longlong_as_double((long long)kbits));
                uint64 r = bcast63_u64(kb);
                int bi = (int)(uint32)(r & 0xffffffffull);
                if ((bi & 63) == lane) excl |= (1ull << (bi >> 6));
                if (lane == 0) {
                    nidx[(size_t)q * KK + k] = bi;
                    size_t oo = ((size_t)q * KK + k) * 3;
                    offs[oo + 0] = __fsub_rn(base[bi], sx);
                    offs[oo + 1] = __fsub_rn(base[NN + bi], sy);
                    offs[oo + 2] = __fsub_rn(base[2 * NN + bi], sz);
                }
            }
        }
        if (!fuse_a) return;
        // wait for ALL short blocks (ptsT + w1t visibility, cross-XCD)
        if (t == 0) {
            while (__hip_atomic_load(&progress[8], __ATOMIC_ACQUIRE,
                                     __HIP_MEMORY_SCOPE_AGENT) < 1584)
                __builtin_amdgcn_s_sleep(16);
        }
        __syncthreads();   // also orders this block's nidx/offs global writes
        // -------- pass_a body for this block's 4 queries --------
        float* cpts = (float*)smu;                 // 2048 floats
        float* red1 = (float*)(smu + 8192);        // 256 floats
        float* red2 = (float*)(smu + 9216);        // 256 floats
        for (int j4 = 0; j4 < 4; j4++) {
            int qq = bq * SS + p0 + j4;
            int slotq = qq & (N_SLOTS - 1);
            stage_pts(ptsT, nidx, qq, bq, t, cpts);
            __syncthreads();
            int c = t & 63, kg = t >> 6;
            float bias = c1_b[c];
            float acc[8];
#pragma unroll
            for (int j = 0; j < 8; j++) acc[j] = bias;
            for (int d4 = 0; d4 < 16; d4++) {
                float w0 = w1t[(4 * d4 + 0) * 64 + c];
                float w1v = w1t[(4 * d4 + 1) * 64 + c];
                float w2v = w1t[(4 * d4 + 2) * 64 + c];
                float w3 = w1t[(4 * d4 + 3) * 64 + c];
#pragma unroll
                for (int j = 0; j < 8; j++) {
                    const float4 p = *(const float4*)&cpts[(kg + 4 * j) * 64 + 4 * d4];
                    acc[j] = fmaf(p.x, w0, acc[j]);
                    acc[j] = fmaf(p.y, w1v, acc[j]);
                    acc[j] = fmaf(p.z, w2v, acc[j]);
                    acc[j] = fmaf(p.w, w3, acc[j]);
                }
            }
#pragma unroll
            for (int j = 0; j < 8; j++)
                f1pre[(size_t)qq * 2048 + j * 256 + t] = acc[j];
            float s1 = 0.f, s2 = 0.f;
#pragma unroll
            for (int j = 0; j < 8; j++) { s1 += acc[j]; s2 += acc[j] * acc[j]; }
            red1[t] = s1;
            red2[t] = s2;
            __syncthreads();
            if (t < 64) {
                atomicAdd(&stats[slotq * ST_STRIDE + ST_S1_C1 + t],
                          red1[t] + red1[t + 64] + red1[t + 128] + red1[t + 192]);
                atomicAdd(&stats[slotq * ST_STRIDE + ST_S2_C1 + t],
                          red2[t] + red2[t + 64] + red2[t + 128] + red2[t + 192]);
            }
            int k0 = t >> 3, c0 = t & 7;
            size_t oo = ((size_t)qq * KK + k0) * 3;
            float h = w0_b[c0];
            h = fmaf(offs[oo + 0], w0_w[c0 * 3 + 0], h);
            h = fmaf(offs[oo + 1], w0_w[c0 * 3 + 1], h);
            h = fmaf(offs[oo + 2], w0_w[c0 * 3 + 2], h);
            __syncthreads();
            red1[t] = h;
            red2[t] = h * h;
            __syncthreads();
            if (t < 8) {
                float a = 0.f, qv = 0.f;
                for (int j = t; j < 256; j += 8) { a += red1[j]; qv += red2[j]; }
                atomicAdd(&stats[slotq * ST_STRIDE + ST_S1_W0 + t], a);
                atomicAdd(&stats[slotq * ST_STRIDE + ST_S2_W0 + t], qv);
            }
        }
    }
}

// ------------------------------------------------------------------
// pass A (tier<2 fallback): conv1 stats + w0 stats; optional f1pre
// ------------------------------------------------------------------
__global__ __launch_bounds__(256) void pass_a(const __hip_bfloat16* __restrict__ ptsT,
                                              const int* __restrict__ nidx,
                                              const float* __restrict__ offs,
                                              const float* __restrict__ w1t,
                                              const float* __restrict__ c1_b,
                                              const float* __restrict__ w0_w,
                                              const float* __restrict__ w0_b,
                                              float* __restrict__ stats,
                                              float* __restrict__ f1pre,
                                              int emit_f1) {
    __shared__ __align__(16) float pts[2048];
    __shared__ float red1[256], red2[256];
    int blk = blockIdx.x, t = threadIdx.x;
    int b = blk >> 10;
    int slot = blk & (N_SLOTS - 1);
    stage_pts(ptsT, nidx, blk, b, t, pts);
    __syncthreads();
    int c = t & 63, kg = t >> 6;
    float bias = c1_b[c];
    float acc[8];
#pragma unroll
    for (int j = 0; j < 8; j++) acc[j] = bias;
    for (int d4 = 0; d4 < 16; d4++) {
        float w0 = w1t[(4 * d4 + 0) * 64 + c];
        float w1v = w1t[(4 * d4 + 1) * 64 + c];
        float w2v = w1t[(4 * d4 + 2) * 64 + c];
        float w3 = w1t[(4 * d4 + 3) * 64 + c];
#pragma unroll
        for (int j = 0; j < 8; j++) {
            const float4 p = *(const float4*)&pts[(kg + 4 * j) * 64 + 4 * d4];
            acc[j] = fmaf(p.x, w0, acc[j]);
            acc[j] = fmaf(p.y, w1v, acc[j]);
            acc[j] = fmaf(p.z, w2v, acc[j]);
            acc[j] = fmaf(p.w, w3, acc[j]);
        }
    }
    if (emit_f1) {
#pragma unroll
        for (int j = 0; j < 8; j++)
            f1pre[(size_t)blk * 2048 + j * 256 + t] = acc[j];
    }
    float s1 = 0.f, s2 = 0.f;
#pragma unroll
    for (int j = 0; j < 8; j++) { s1 += acc[j]; s2 += acc[j] * acc[j]; }
    red1[t] = s1;
    red2[t] = s2;
    __syncthreads();
    if (t < 64) {
        atomicAdd(&stats[slot * ST_STRIDE + ST_S1_C1 + t],
                  red1[t] + red1[t + 64] + red1[t + 128] + red1[t + 192]);
        atomicAdd(&stats[slot * ST_STRIDE + ST_S2_C1 + t],
                  red2[t] + red2[t + 64] + red2[t + 128] + red2[t + 192]);
    }
    int k0 = t >> 3, c0 = t & 7;
    size_t oo = ((size_t)blk * KK + k0) * 3;
    float h = w0_b[c0];
    h = fmaf(offs[oo + 0], w0_w[c0 * 3 + 0], h);
    h = fmaf(offs[oo + 1], w0_w[c0 * 3 + 1], h);
    h = fmaf(offs[oo + 2], w0_w[c0 * 3 + 2], h);
    __syncthreads();
    red1[t] = h;
    red2[t] = h * h;
    __syncthreads();
    if (t < 8) {
        float a = 0.f, q = 0.f;
        for (int j = t; j < 256; j += 8) { a += red1[j]; q += red2[j]; }
        atomicAdd(&stats[slot * ST_STRIDE + ST_S1_W0 + t], a);
        atomicAdd(&stats[slot * ST_STRIDE + ST_S2_W0 + t], q);
    }
}

// ------------------------------------------------------------------
// finalize BN(s) from slotted stats
// ------------------------------------------------------------------
__device__ __forceinline__ void fin_one(const float* stats, float* params,
                                        const float* g, const float* be,
                                        int s1o, int s2o, int ao, int co,
                                        int nch, float inv, int t) {
    if (t < nch) {
        float s1 = 0.f, s2 = 0.f;
        for (int s = 0; s < N_SLOTS; s++) {
            s1 += stats[s * ST_STRIDE + s1o + t];
            s2 += stats[s * ST_STRIDE + s2o + t];
        }
        float m = s1 * inv;
        float v = s2 * inv - m * m;
        float a = g[t] * rsqrtf(v + 1e-5f);
        params[ao + t] = a;
        params[co + t] = be[t] - m * a;
    }
}

__global__ void finalize_bn(const float* __restrict__ stats, float* __restrict__ params,
                            const float* __restrict__ g, const float* __restrict__ be,
                            int s1o, int s2o, int ao, int co, int nch, float inv) {
    fin_one(stats, params, g, be, s1o, s2o, ao, co, nch, inv, threadIdx.x);
}

__global__ void finalize_two(const float* __restrict__ stats, float* __restrict__ params,
                             const float* __restrict__ gA, const float* __restrict__ beA,
                             int s1A, int s2A, int aA, int cA, int nA, float invA,
                             const float* __restrict__ gB, const float* __restrict__ beB,
                             int s1B, int s2B, int aB, int cB, int nB, float invB) {
    if (blockIdx.x == 0)
        fin_one(stats, params, gA, beA, s1A, s2A, aA, cA, nA, invA, threadIdx.x);
    else
        fin_one(stats, params, gB, beB, s1B, s2B, aB, cB, nB, invB, threadIdx.x);
}

// ------------------------------------------------------------------
// pass B (tier-1 fallback): conv1 recompute + bn1relu -> f1; conv2
// stats; w1 stats
// ------------------------------------------------------------------
__global__ __launch_bounds__(256) void pass_b(const __hip_bfloat16* __restrict__ ptsT,
                                              const int* __restrict__ nidx,
                                              const float* __restrict__ offs,
                                              const float* __restrict__ w1t,
                                              const float* __restrict__ c1_b,
                                              const float* __restrict__ w2t,
                                              const float* __restrict__ c2_b,
                                              const float* __restrict__ w0_w,
                                              const float* __restrict__ w0_b,
                                              const float* __restrict__ w1_w,
                                              const float* __restrict__ w1_b,
                                              const float* __restrict__ params,
                                              float* __restrict__ stats) {
    __shared__ __align__(16) float pts[2048];
    __shared__ __align__(16) float f1[2048];
    __shared__ float red1[256], red2[256];
    int blk = blockIdx.x, t = threadIdx.x;
    int b = blk >> 10;
    int slot = blk & (N_SLOTS - 1);
    stage_pts(ptsT, nidx, blk, b, t, pts);
    __syncthreads();
    {
        int c = t & 63, kg = t >> 6;
        float a1 = params[PA_A_C1 + c], cc1 = params[PA_C_C1 + c], bias = c1_b[c];
        float acc[8];
#pragma unroll
        for (int j = 0; j < 8; j++) acc[j] = bias;
        for (int d4 = 0; d4 < 16; d4++) {
            float w0 = w1t[(4 * d4 + 0) * 64 + c];
            float w1v = w1t[(4 * d4 + 1) * 64 + c];
            float w2v = w1t[(4 * d4 + 2) * 64 + c];
            float w3 = w1t[(4 * d4 + 3) * 64 + c];
#pragma unroll
            for (int j = 0; j < 8; j++) {
                const float4 p = *(const float4*)&pts[(kg + 4 * j) * 64 + 4 * d4];
                acc[j] = fmaf(p.x, w0, acc[j]);
                acc[j] = fmaf(p.y, w1v, acc[j]);
                acc[j] = fmaf(p.z, w2v, acc[j]);
                acc[j] = fmaf(p.w, w3, acc[j]);
            }
        }
#pragma unroll
        for (int j = 0; j < 8; j++)
            f1[(kg + 4 * j) * 64 + c] = fmaxf(fmaf(acc[j], a1, cc1), 0.f);
    }
    __syncthreads();
    {
        int c = t & 127, kg = t >> 7;
        float bias = c2_b[c];
        float acc[16];
#pragma unroll
        for (int j = 0; j < 16; j++) acc[j] = bias;
        for (int d4 = 0; d4 < 16; d4++) {
            float w0 = w2t[(4 * d4 + 0) * 128 + c];
            float w1v = w2t[(4 * d4 + 1) * 128 + c];
            float w2v = w2t[(4 * d4 + 2) * 128 + c];
            float w3 = w2t[(4 * d4 + 3) * 128 + c];
#pragma unroll
            for (int j = 0; j < 16; j++) {
                const float4 p = *(const float4*)&f1[(kg + 2 * j) * 64 + 4 * d4];
                acc[j] = fmaf(p.x, w0, acc[j]);
                acc[j] = fmaf(p.y, w1v, acc[j]);
                acc[j] = fmaf(p.z, w2v, acc[j]);
                acc[j] = fmaf(p.w, w3, acc[j]);
            }
        }
        float s1 = 0.f, s2 = 0.f;
#pragma unroll
        for (int j = 0; j < 16; j++) { s1 += acc[j]; s2 += acc[j] * acc[j]; }
        red1[t] = s1;
        red2[t] = s2;
    }
    __syncthreads();
    if (t < 128) {
        atomicAdd(&stats[slot * ST_STRIDE + ST_S1_C2 + t], red1[t] + red1[t + 128]);
        atomicAdd(&stats[slot * ST_STRIDE + ST_S2_C2 + t], red2[t] + red2[t + 128]);
    }
    {
        int k0 = t >> 3, c0 = t & 7;
        size_t oo = ((size_t)blk * KK + k0) * 3;
        float o0 = offs[oo], o1 = offs[oo + 1], o2 = offs[oo + 2];
        float h0[8];
#pragma unroll
        for (int j = 0; j < 8; j++) {
            float hh = w0_b[j];
            hh = fmaf(o0, w0_w[j * 3 + 0], hh);
            hh = fmaf(o1, w0_w[j * 3 + 1], hh);
            hh = fmaf(o2, w0_w[j * 3 + 2], hh);
            h0[j] = fmaxf(fmaf(hh, params[PA_A_W0 + j], params[PA_C_W0 + j]), 0.f);
        }
        float h = w1_b[c0];
#pragma unroll
        for (int j = 0; j < 8; j++) h = fmaf(h0[j], w1_w[c0 * 8 + j], h);
        __syncthreads();
        red1[t] = h;
        red2[t] = h * h;
        __syncthreads();
        if (t < 8) {
            float a = 0.f, q = 0.f;
            for (int j = t; j < 256; j += 8) { a += red1[j]; q += red2[j]; }
            atomicAdd(&stats[slot * ST_STRIDE + ST_S1_W1 + t], a);
            atomicAdd(&stats[slot * ST_STRIDE + ST_S2_W1 + t], q);
        }
    }
}

// ------------------------------------------------------------------
// pass B2 (tier-2): read f1pre, bn1relu, conv2 -> f2pre + c2 stats;
// w1 stats. No gather, no conv1 recompute.
// ------------------------------------------------------------------
__global__ __launch_bounds__(256) void pass_b2(const float* __restrict__ f1pre,
                                               const float* __restrict__ offs,
                                               const float* __restrict__ w2t,
                                               const float* __restrict__ c2_b,
                                               const float* __restrict__ w0_w,
                                               const float* __restrict__ w0_b,
                                               const float* __restrict__ w1_w,
                                               const float* __restrict__ w1_b,
                                               const float* __restrict__ params,
                                               float* __restrict__ stats,
                                               float* __restrict__ f2pre) {
    __shared__ __align__(16) float f1[2048];
    __shared__ float red1[256], red2[256];
    int blk = blockIdx.x, t = threadIdx.x;
    int slot = blk & (N_SLOTS - 1);
    {
        int c = t & 63;
        float a1 = params[PA_A_C1 + c], cc1 = params[PA_C_C1 + c];
#pragma unroll
        for (int i = 0; i < 8; i++) {
            float v = f1pre[(size_t)blk * 2048 + i * 256 + t];
            f1[i * 256 + t] = fmaxf(fmaf(v, a1, cc1), 0.f);
        }
    }
    __syncthreads();
    {
        int c = t & 127, kg = t >> 7;
        float bias = c2_b[c];
        float acc[16];
#pragma unroll
        for (int j = 0; j < 16; j++) acc[j] = bias;
        for (int d4 = 0; d4 < 16; d4++) {
            float w0 = w2t[(4 * d4 + 0) * 128 + c];
            float w1v = w2t[(4 * d4 + 1) * 128 + c];
            float w2v = w2t[(4 * d4 + 2) * 128 + c];
            float w3 = w2t[(4 * d4 + 3) * 128 + c];
#pragma unroll
            for (int j = 0; j < 16; j++) {
                const float4 p = *(const float4*)&f1[(kg + 2 * j) * 64 + 4 * d4];
                acc[j] = fmaf(p.x, w0, acc[j]);
                acc[j] = fmaf(p.y, w1v, acc[j]);
                acc[j] = fmaf(p.z, w2v, acc[j]);
                acc[j] = fmaf(p.w, w3, acc[j]);
            }
        }
#pragma unroll
        for (int j = 0; j < 16; j++)
            f2pre[(size_t)blk * 4096 + j * 256 + t] = acc[j];
        float s1 = 0.f, s2 = 0.f;
#pragma unroll
        for (int j = 0; j < 16; j++) { s1 += acc[j]; s2 += acc[j] * acc[j]; }
        red1[t] = s1;
        red2[t] = s2;
    }
    __syncthreads();
    if (t < 128) {
        atomicAdd(&stats[slot * ST_STRIDE + ST_S1_C2 + t], red1[t] + red1[t + 128]);
        atomicAdd(&stats[slot * ST_STRIDE + ST_S2_C2 + t], red2[t] + red2[t + 128]);
    }
    {
        int k0 = t >> 3, c0 = t & 7;
        size_t oo = ((size_t)blk * KK + k0) * 3;
        float o0 = offs[oo], o1 = offs[oo + 1], o2 = offs[oo + 2];
        float h0[8];
#pragma unroll
        for (int j = 0; j < 8; j++) {
            float hh = w0_b[j];
            hh = fmaf(o0, w0_w[j * 3 + 0], hh);
            hh = fmaf(o1, w0_w[j * 3 + 1], hh);
            hh = fmaf(o2, w0_w[j * 3 + 2], hh);
            h0[j] = fmaxf(fmaf(hh, params[PA_A_W0 + j], params[PA_C_W0 + j]), 0.f);
        }
        float h = w1_b[c0];
#pragma unroll
        for (int j = 0; j < 8; j++) h = fmaf(h0[j], w1_w[c0 * 8 + j], h);
        __syncthreads();
        red1[t] = h;
        red2[t] = h * h;
        __syncthreads();
        if (t < 8) {
            float a = 0.f, q = 0.f;
            for (int j = t; j < 256; j += 8) { a += red1[j]; q += red2[j]; }
            atomicAdd(&stats[slot * ST_STRIDE + ST_S1_W1 + t], a);
            atomicAdd(&stats[slot * ST_STRIDE + ST_S2_W1 + t], q);
        }
    }
}

// ------------------------------------------------------------------
// w2 stats (unchanged)
// ------------------------------------------------------------------
__global__ __launch_bounds__(256) void pass_w2(const float* __restrict__ offs,
                                               const float* __restrict__ w0_w,
                                               const float* __restrict__ w0_b,
                                               const float* __restrict__ w1_w,
                                               const float* __restrict__ w1_b,
                                               const float* __restrict__ w2_w,
                                               const float* __restrict__ w2_b,
                                               const float* __restrict__ params,
                                               float* __restrict__ stats) {
    int i = blockIdx.x * 256 + threadIdx.x;
    int slot = blockIdx.x & (N_SLOTS - 1);
    size_t oo = (size_t)i * 3;
    float o0 = offs[oo], o1 = offs[oo + 1], o2 = offs[oo + 2];
    float h0[8], h1[8];
#pragma unroll
    for (int j = 0; j < 8; j++) {
        float hh = w0_b[j];
        hh = fmaf(o0, w0_w[j * 3 + 0], hh);
        hh = fmaf(o1, w0_w[j * 3 + 1], hh);
        hh = fmaf(o2, w0_w[j * 3 + 2], hh);
        h0[j] = fmaxf(fmaf(hh, params[PA_A_W0 + j], params[PA_C_W0 + j]), 0.f);
    }
#pragma unroll
    for (int j = 0; j < 8; j++) {
        float hh = w1_b[j];
#pragma unroll
        for (int q = 0; q < 8; q++) hh = fmaf(h0[q], w1_w[j * 8 + q], hh);
        h1[j] = fmaxf(fmaf(hh, params[PA_A_W1 + j], params[PA_C_W1 + j]), 0.f);
    }
#pragma unroll
    for (int c = 0; c < 16; c++) {
        float h = w2_b[c];
#pragma unroll
        for (int q = 0; q < 8; q++) h = fmaf(h1[q], w2_w[c * 8 + q], h);
        float v = wave_sum_f32(h);
        float s = wave_sum_f32(h * h);
        if ((threadIdx.x & 63) == LIN_WRITER) {
            atomicAdd(&stats[slot * ST_STRIDE + ST_S1_W2 + c], v);
            atomicAdd(&stats[slot * ST_STRIDE + ST_S2_W2 + c], s);
        }
    }
}

// ------------------------------------------------------------------
// weightnet device helper (shared by tails)
// ------------------------------------------------------------------
__device__ __forceinline__ void weightnet_to_lds(const float* __restrict__ offs,
                                                 const float* __restrict__ w0_w,
                                                 const float* __restrict__ w0_b,
                                                 const float* __restrict__ w1_w,
                                                 const float* __restrict__ w1_b,
                                                 const float* __restrict__ w2_w,
                                                 const float* __restrict__ w2_b,
                                                 const float* __restrict__ params,
                                                 int blk, int t, float* wg) {
    for (int idx = t; idx < KK * 16; idx += 256) {
        int k = idx >> 4, cw = idx & 15;
        size_t oo = ((size_t)blk * KK + k) * 3;
        float o0 = offs[oo], o1 = offs[oo + 1], o2 = offs[oo + 2];
        float h0[8], h1[8];
#pragma unroll
        for (int j = 0; j < 8; j++) {
            float hh = w0_b[j];
            hh = fmaf(o0, w0_w[j * 3 + 0], hh);
            hh = fmaf(o1, w0_w[j * 3 + 1], hh);
            hh = fmaf(o2, w0_w[j * 3 + 2], hh);
            h0[j] = fmaxf(fmaf(hh, params[PA_A_W0 + j], params[PA_C_W0 + j]), 0.f);
        }
#pragma unroll
        for (int j = 0; j < 8; j++) {
            float hh = w1_b[j];
#pragma unroll
            for (int q = 0; q < 8; q++) hh = fmaf(h0[q], w1_w[j * 8 + q], hh);
            h1[j] = fmaxf(fmaf(hh, params[PA_A_W1 + j], params[PA_C_W1 + j]), 0.f);
        }
        float h = w2_b[cw];
#pragma unroll
        for (int q = 0; q < 8; q++) h = fmaf(h1[q], w2_w[cw * 8 + q], h);
        wg[idx] = fmaxf(fmaf(h, params[PA_A_W2 + cw], params[PA_C_W2 + cw]), 0.f);
    }
}

// ------------------------------------------------------------------
// tail_nl2 (tier-2): read f2pre + bn2relu -> LDS; weightnet; einsum;
// feats -> global.
// ------------------------------------------------------------------
__global__ __launch_bounds__(256) void tail_nl2(const float* __restrict__ f2pre,
                                                const float* __restrict__ offs,
                                                const float* __restrict__ w0_w,
                                                const float* __restrict__ w0_b,
                                                const float* __restrict__ w1_w,
                                                const float* __restrict__ w1_b,
                                                const float* __restrict__ w2_w,
                                                const float* __restrict__ w2_b,
                                                const float* __restrict__ params,
                                                float* __restrict__ featsF) {
    __shared__ __align__(16) float sm[6656];
    float* f2    = sm;            // [4096]
    float* wg    = sm + 4096;     // [512]
    float* feats = sm + 4608;     // [2048]
    int blk = blockIdx.x, t = threadIdx.x;
    weightnet_to_lds(offs, w0_w, w0_b, w1_w, w1_b, w2_w, w2_b, params, blk, t, wg);
    {
        int c = t & 127;
        float a2 = params[PA_A_C2 + c], cc2 = params[PA_C_C2 + c];
#pragma unroll
        for (int i = 0; i < 16; i++) {
            float v = f2pre[(size_t)blk * 4096 + i * 256 + t];
            f2[i * 256 + t] = fmaxf(fmaf(v, a2, cc2), 0.f);
        }
    }
    __syncthreads();
    {
        int cc = t & 127, wh = t >> 7;
        float acc[8];
#pragma unroll
        for (int i = 0; i < 8; i++) acc[i] = 0.f;
        for (int k = 0; k < KK; k++) {
            float fv = f2[k * 128 + cc];
            const float4 wa = *(const float4*)&wg[k * 16 + 8 * wh];
            const float4 wb = *(const float4*)&wg[k * 16 + 8 * wh + 4];
            acc[0] = fmaf(fv, wa.x, acc[0]);
            acc[1] = fmaf(fv, wa.y, acc[1]);
            acc[2] = fmaf(fv, wa.z, acc[2]);
            acc[3] = fmaf(fv, wa.w, acc[3]);
            acc[4] = fmaf(fv, wb.x, acc[4]);
            acc[5] = fmaf(fv, wb.y, acc[5]);
            acc[6] = fmaf(fv, wb.z, acc[6]);
            acc[7] = fmaf(fv, wb.w, acc[7]);
        }
        *(float4*)&feats[cc * 16 + 8 * wh]     = *(float4*)&acc[0];
        *(float4*)&feats[cc * 16 + 8 * wh + 4] = *(float4*)&acc[4];
    }
    __syncthreads();
#pragma unroll
    for (int i = 0; i < 8; i++)
        featsF[(size_t)blk * 2048 + i * 256 + t] = feats[i * 256 + t];
}

// ------------------------------------------------------------------
// fused_tail_nl (tier-1): full recompute tail
// ------------------------------------------------------------------
__global__ __launch_bounds__(256) void fused_tail_nl(
        const __hip_bfloat16* __restrict__ ptsT, const int* __restrict__ nidx,
        const float* __restrict__ offs,
        const float* __restrict__ w1t, const float* __restrict__ c1_b,
        const float* __restrict__ w2t, const float* __restrict__ c2_b,
        const float* __restrict__ w0_w, const float* __restrict__ w0_b,
        const float* __restrict__ w1_w, const float* __restrict__ w1_b,
        const float* __restrict__ w2_w, const float* __restrict__ w2_b,
        const float* __restrict__ params, float* __restrict__ featsF) {
    __shared__ __align__(16) float sm[8704];
    float* pts   = sm;
    float* f1    = sm + 2048;
    float* f2    = sm + 4096;
    float* wg    = sm + 8192;
    int blk = blockIdx.x, t = threadIdx.x;
    int b = blk >> 10;
    stage_pts(ptsT, nidx, blk, b, t, pts);
    weightnet_to_lds(offs, w0_w, w0_b, w1_w, w1_b, w2_w, w2_b, params, blk, t, wg);
    __syncthreads();
    {
        int c = t & 63, kg = t >> 6;
        float a1 = params[PA_A_C1 + c], cc1 = params[PA_C_C1 + c], bias = c1_b[c];
        float acc[8];
#pragma unroll
        for (int j = 0; j < 8; j++) acc[j] = bias;
        for (int d4 = 0; d4 < 16; d4++) {
            float w0 = w1t[(4 * d4 + 0) * 64 + c];
            float w1v = w1t[(4 * d4 + 1) * 64 + c];
            float w2v = w1t[(4 * d4 + 2) * 64 + c];
            float w3 = w1t[(4 * d4 + 3) * 64 + c];
#pragma unroll
            for (int j = 0; j < 8; j++) {
                const float4 p = *(const float4*)&pts[(kg + 4 * j) * 64 + 4 * d4];
                acc[j] = fmaf(p.x, w0, acc[j]);
                acc[j] = fmaf(p.y, w1v, acc[j]);
                acc[j] = fmaf(p.z, w2v, acc[j]);
                acc[j] = fmaf(p.w, w3, acc[j]);
            }
        }
#pragma unroll
        for (int j = 0; j < 8; j++)
            f1[(kg + 4 * j) * 64 + c] = fmaxf(fmaf(acc[j], a1, cc1), 0.f);
    }
    __syncthreads();
    {
        int c = t & 127, kg = t >> 7;
        float a2 = params[PA_A_C2 + c], cc2 = params[PA_C_C2 + c], bias = c2_b[c];
        float acc[16];
#pragma unroll
        for (int j = 0; j < 16; j++) acc[j] = bias;
        for (int d4 = 0; d4 < 16; d4++) {
            float w0 = w2t[(4 * d4 + 0) * 128 + c];
            float w1v = w2t[(4 * d4 + 1) * 128 + c];
            float w2v = w2t[(4 * d4 + 2) * 128 + c];
            float w3 = w2t[(4 * d4 + 3) * 128 + c];
#pragma unroll
            for (int j = 0; j < 16; j++) {
                const float4 p = *(const float4*)&f1[(kg + 2 * j) * 64 + 4 * d4];
                acc[j] = fmaf(p.x, w0, acc[j]);
                acc[j] = fmaf(p.y, w1v, acc[j]);
                acc[j] = fmaf(p.z, w2v, acc[j]);
                acc[j] = fmaf(p.w, w3, acc[j]);
            }
        }
#pragma unroll
        for (int j = 0; j < 16; j++)
            f2[(kg + 2 * j) * 128 + c] = fmaxf(fmaf(acc[j], a2, cc2), 0.f);
    }
    __syncthreads();
    {
        int cc = t & 127, wh = t >> 7;
        float acc[8];
#pragma unroll
        for (int i = 0; i < 8; i++) acc[i] = 0.f;
        for (int k = 0; k < KK; k++) {
            float fv = f2[k * 128 + cc];
            const float4 wa = *(const float4*)&wg[k * 16 + 8 * wh];
            const float4 wb = *(const float4*)&wg[k * 16 + 8 * wh + 4];
            acc[0] = fmaf(fv, wa.x, acc[0]);
            acc[1] = fmaf(fv, wa.y, acc[1]);
            acc[2] = fmaf(fv, wa.z, acc[2]);
            acc[3] = fmaf(fv, wa.w, acc[3]);
            acc[4] = fmaf(fv, wb.x, acc[4]);
            acc[5] = fmaf(fv, wb.y, acc[5]);
            acc[6] = fmaf(fv, wb.z, acc[6]);
            acc[7] = fmaf(fv, wb.w, acc[7]);
        }
        *(float4*)&pts[cc * 16 + 8 * wh]     = *(float4*)&acc[0];
        *(float4*)&pts[cc * 16 + 8 * wh + 4] = *(float4*)&acc[4];
    }
    __syncthreads();
#pragma unroll
    for (int i = 0; i < 8; i++)
        featsF[(size_t)blk * 2048 + i * 256 + t] = sm[i * 256 + t];
}

// ------------------------------------------------------------------
// linear_mm16: Y = feats . linB^T + lin_b via MFMA hi/lo bf16 split.
// 16-query tiles, double-buffered LDS, one barrier per K-chunk.
// ------------------------------------------------------------------
__global__ __launch_bounds__(256) void linear_mm16(const float* __restrict__ featsF,
                                                   const __hip_bfloat16* __restrict__ linB,
                                                   const float* __restrict__ lin_b,
                                                   float* __restrict__ stats,
                                                   float* __restrict__ ypre) {
    __shared__ __align__(16) unsigned short Ah[2][16 * 72];
    __shared__ __align__(16) unsigned short Al[2][16 * 72];
    __shared__ __align__(16) unsigned short Bsm[2][128 * 72];
    int t = threadIdx.x;
    int q0 = blockIdx.x * 16;
    int slot = blockIdx.x & (N_SLOTS - 1);
    int qa = t >> 4, pa = t & 15;
    int ob = t >> 1, pb = t & 1;
    int lane = t & 63, w = t >> 6;
    int lg = lane >> 4, ln = lane & 15;
    int qb_base = q0 + lg * 4;

    f32x4v acc0 = {0.f, 0.f, 0.f, 0.f};
    f32x4v acc1 = {0.f, 0.f, 0.f, 0.f};

    const uint4* gA0 = (const uint4*)(featsF + (size_t)(q0 + qa) * 2048);
    const uint4* gB0 = (const uint4*)(linB + (size_t)ob * 2048);

    uint4 ra, rb0, rb1, rb2, rb3;
    ra  = gA0[pa];
    rb0 = gB0[pb * 4 + 0];
    rb1 = gB0[pb * 4 + 1];
    rb2 = gB0[pb * 4 + 2];
    rb3 = gB0[pb * 4 + 3];

    for (int kc = 0; kc < 32; kc++) {
        int buf = kc & 1;
        {
            float f0 = __uint_as_float(ra.x), f1v = __uint_as_float(ra.y);
            float f2v = __uint_as_float(ra.z), f3 = __uint_as_float(ra.w);
            uint32 h0 = bf16rne(f0), h1 = bf16rne(f1v), h2 = bf16rne(f2v), h3 = bf16rne(f3);
            uint2 hv;
            hv.x = h0 | (h1 << 16); hv.y = h2 | (h3 << 16);
            *(uint2*)&Ah[buf][qa * 72 + pa * 4] = hv;
            uint32 l0 = bf16rne(f0 - __uint_as_float(h0 << 16));
            uint32 l1 = bf16rne(f1v - __uint_as_float(h1 << 16));
            uint32 l2 = bf16rne(f2v - __uint_as_float(h2 << 16));
            uint32 l3 = bf16rne(f3 - __uint_as_float(h3 << 16));
            uint2 lv;
            lv.x = l0 | (l1 << 16); lv.y = l2 | (l3 << 16);
            *(uint2*)&Al[buf][qa * 72 + pa * 4] = lv;
            *(uint4*)&Bsm[buf][ob * 72 + pb * 32 + 0]  = rb0;
            *(uint4*)&Bsm[buf][ob * 72 + pb * 32 + 8]  = rb1;
            *(uint4*)&Bsm[buf][ob * 72 + pb * 32 + 16] = rb2;
            *(uint4*)&Bsm[buf][ob * 72 + pb * 32 + 24] = rb3;
        }
        __syncthreads();
        if (kc + 1 < 32) {
            ra  = gA0[(kc + 1) * 16 + pa];
            rb0 = gB0[(kc + 1) * 8 + pb * 4 + 0];
            rb1 = gB0[(kc + 1) * 8 + pb * 4 + 1];
            rb2 = gB0[(kc + 1) * 8 + pb * 4 + 2];
            rb3 = gB0[(kc + 1) * 8 + pb * 4 + 3];
        }
#pragma unroll
        for (int s = 0; s < 2; s++) {
            int ko = s * 32 + lg * 8;
            bf16x8 ah = *(const bf16x8*)&Ah[buf][ln * 72 + ko];
            bf16x8 al = *(const bf16x8*)&Al[buf][ln * 72 + ko];
            bf16x8 b0 = *(const bf16x8*)&Bsm[buf][(w * 32 + 0  + ln) * 72 + ko];
            bf16x8 b1 = *(const bf16x8*)&Bsm[buf][(w * 32 + 16 + ln) * 72 + ko];
            acc0 = __builtin_amdgcn_mfma_f32_16x16x32_bf16(ah, b0, acc0, 0, 0, 0);
            acc0 = __builtin_amdgcn_mfma_f32_16x16x32_bf16(al, b0, acc0, 0, 0, 0);
            acc1 = __builtin_amdgcn_mfma_f32_16x16x32_bf16(ah, b1, acc1, 0, 0, 0);
            acc1 = __builtin_amdgcn_mfma_f32_16x16x32_bf16(al, b1, acc1, 0, 0, 0);
        }
    }
    {
        int o0 = w * 32 + 0  + ln;
        int o1 = w * 32 + 16 + ln;
        float lb0 = lin_b[o0], lb1 = lin_b[o1];
        float s1a = 0.f, s2a = 0.f, s1b = 0.f, s2b = 0.f;
#pragma unroll
        for (int r = 0; r < 4; r++) {
            size_t qrow = (size_t)(qb_base + r) * 128;
            float y0 = acc0[r] + lb0;
            float y1 = acc1[r] + lb1;
            ypre[qrow + o0] = y0;
            ypre[qrow + o1] = y1;
            s1a += y0; s2a += y0 * y0;
            s1b += y1; s2b += y1 * y1;
        }
        atomicAdd(&stats[slot * ST_STRIDE + ST_S1_Y + o0], s1a);
        atomicAdd(&stats[slot * ST_STRIDE + ST_S2_Y + o0], s2a);
        atomicAdd(&stats[slot * ST_STRIDE + ST_S1_Y + o1], s1b);
        atomicAdd(&stats[slot * ST_STRIDE + ST_S2_Y + o1], s2b);
    }
}

// ------------------------------------------------------------------
// final BN + relu + tiled transpose write to out1 [B,128,S]
// ------------------------------------------------------------------
__global__ __launch_bounds__(256) void bn_y(const float* __restrict__ ypre,
                                            const float* __restrict__ stats,
                                            const float* __restrict__ lg,
                                            const float* __restrict__ lb,
                                            float* __restrict__ out1) {
    __shared__ float tile[64 * 133];
    __shared__ float pa[128], pc[128];
    int blk = blockIdx.x;
    int b = blk >> 4;
    int s0 = (blk & 15) * 64;
    int t = threadIdx.x;
    if (t < 128) {
        float s1 = 0.f, s2 = 0.f;
        for (int s = 0; s < N_SLOTS; s++) {
            s1 += stats[s * ST_STRIDE + ST_S1_Y + t];
            s2 += stats[s * ST_STRIDE + ST_S2_Y + t];
        }
        const float inv = 1.f / (float)BS;
        float m = s1 * inv;
        float v = s2 * inv - m * m;
        float a = lg[t] * rsqrtf(v + 1e-5f);
        pa[t] = a;
        pc[t] = lb[t] - m * a;
    }
#pragma unroll
    for (int i = 0; i < 32; i++) {
        int idx = i * 256 + t;
        int s = idx >> 7, c = idx & 127;
        tile[s * 133 + c] = ypre[(((size_t)b << 10) + s0 + s) * 128 + c];
    }
    __syncthreads();
#pragma unroll
    for (int i = 0; i < 32; i++) {
        int idx = i * 256 + t;
        int c = idx >> 6, s = idx & 63;
        float v = tile[s * 133 + c];
        out1[((size_t)b * 128 + c) * 1024 + s0 + s] =
            fmaxf(fmaf(v, pa[c], pc[c]), 0.f);
    }
}

// ------------------------------------------------------------------
extern "C" void kernel_launch(void* const* d_in, const int* in_sizes, int n_in,
                              void* d_out, int out_size, void* d_ws, size_t ws_size,
                              hipStream_t stream) {
    const float* xyz    = (const float*)d_in[0];
    const float* points = (const float*)d_in[1];
    const float* c1_w = (const float*)d_in[2];
    const float* c1_b = (const float*)d_in[3];
    const float* g1   = (const float*)d_in[4];
    const float* b1   = (const float*)d_in[5];
    const float* c2_w = (const float*)d_in[6];
    const float* c2_b = (const float*)d_in[7];
    const float* g2   = (const float*)d_in[8];
    const float* b2   = (const float*)d_in[9];
    const float* w0_w = (const float*)d_in[10];
    const float* w0_b = (const float*)d_in[11];
    const float* w0_g = (const float*)d_in[12];
    const float* w0_be= (const float*)d_in[13];
    const float* w1_w = (const float*)d_in[14];
    const float* w1_b = (const float*)d_in[15];
    const float* w1_g = (const float*)d_in[16];
    const float* w1_be= (const float*)d_in[17];
    const float* w2_w = (const float*)d_in[18];
    const float* w2_b = (const float*)d_in[19];
    const float* w2_g = (const float*)d_in[20];
    const float* w2_be= (const float*)d_in[21];
    const float* lin_w= (const float*)d_in[22];
    const float* lin_b= (const float*)d_in[23];
    const float* lg   = (const float*)d_in[24];
    const float* lb   = (const float*)d_in[25];

    float* out0 = (float*)d_out;
    float* out1 = out0 + (size_t)BB * 3 * SS;

    char* wsb = (char*)d_ws;
    int*   nidx    = (int*)(wsb + 0);                         // 1,048,576
    float* offs    = (float*)(wsb + 1048576);                 // 3,145,728
    float* new_xyz = (float*)(wsb + 4194304);                 // 98,304
    float* ypre    = (float*)(wsb + 4292608);                 // 4,194,304
    __hip_bfloat16* ptsT = (__hip_bfloat16*)(wsb + 8486912);  // 4,194,304
    float* w1t     = (float*)(wsb + 12681216);                // 16,384
    float* w2t     = (float*)(wsb + 12697600);                // 32,768
    __hip_bfloat16* linB = (__hip_bfloat16*)(wsb + 12730368); // 524,288
    float* stats   = (float*)(wsb + 13254656);                // 180,224
    float* params  = (float*)(wsb + 13434880);                // 2,816 (floats [448,704) unused)
    int*   progress= (int*)(wsb + 13436672);                  // 64 B inside unused params tail
    float* featsF  = (float*)(wsb + 13437696);                // 67,108,864
    float* f1pre   = featsF;                                  // alias: f1pre dead before feats written
    float* f2pre   = (float*)(wsb + 80546560);                // 134,217,728 (tier-2 only)

    const size_t NEED1 = 13437696ull + 67108864ull;               // 80,546,560
    const size_t NEED2 = 80546560ull + 134217728ull;              // 214,764,288
    const int tier = (ws_size >= NEED2) ? 2 : (ws_size >= NEED1) ? 1 : 0;

    hipMemsetAsync(stats, 0, N_SLOTS * ST_STRIDE * sizeof(float), stream);
    hipMemsetAsync(progress, 0, 64, stream);

    // prep + FPS + streaming kNN (+fused pass_a at tier 2); 82KB LDS
    // forces 1 block/CU so FPS runs on exclusive CUs
    prep_fps_knn<<<3640, 256, 0, stream>>>(points, ptsT, c1_w, c2_w, lin_w, w1t, w2t,
                                           linB, xyz, new_xyz, out0,
                                           progress, nidx, offs,
                                           c1_b, w0_w, w0_b, stats, f1pre,
                                           tier == 2 ? 1 : 0);

    if (tier != 2) {
        pass_a<<<BS, 256, 0, stream>>>(ptsT, nidx, offs, w1t, c1_b, w0_w, w0_b, stats,
                                       f1pre, 0);
    }
    finalize_two<<<2, 128, 0, stream>>>(stats, params,
                                        g1, b1, ST_S1_C1, ST_S2_C1, PA_A_C1, PA_C_C1, 64, 1.f / BSK,
                                        w0_g, w0_be, ST_S1_W0, ST_S2_W0, PA_A_W0, PA_C_W0, 8, 1.f / BSK);

    if (tier == 2) {
        pass_b2<<<BS, 256, 0, stream>>>(f1pre, offs, w2t, c2_b,
                                        w0_w, w0_b, w1_w, w1_b, params, stats, f2pre);
    } else {
        pass_b<<<BS, 256, 0, stream>>>(ptsT, nidx, offs, w1t, c1_b, w2t, c2_b,
                                       w0_w, w0_b, w1_w, w1_b, params, stats);
    }
    finalize_two<<<2, 128, 0, stream>>>(stats, params,
                                        g2, b2, ST_S1_C2, ST_S2_C2, PA_A_C2, PA_C_C2, 128, 1.f / BSK,
                                        w1_g, w1_be, ST_S1_W1, ST_S2_W1, PA_A_W1, PA_C_W1, 8, 1.f / BSK);

    pass_w2<<<BSK / 256, 256, 0, stream>>>(offs, w0_w, w0_b, w1_w, w1_b, w2_w, w2_b,
                                           params, stats);
    finalize_bn<<<1, 128, 0, stream>>>(stats, params, w2_g, w2_be,
                                       ST_S1_W2, ST_S2_W2, PA_A_W2, PA_C_W2, 16, 1.f / BSK);

    if (tier == 2) {
        tail_nl2<<<BS, 256, 0, stream>>>(f2pre, offs, w0_w, w0_b, w1_w, w1_b,
                                         w2_w, w2_b, params, featsF);
        linear_mm16<<<BS / 16, 256, 0, stream>>>(featsF, linB, lin_b, stats, ypre);
    } else {
        fused_tail_nl<<<BS, 256, 0, stream>>>(ptsT, nidx, offs, w1t, c1_b, w2t, c2_b,
                                              w0_w, w0_b, w1_w, w1_b, w2_w, w2_b,
                                              params, featsF);
        linear_mm16<<<BS / 16, 256, 0, stream>>>(featsF, linB, lin_b, stats, ypre);
    }

    bn_y<<<BB * 16, 256, 0, stream>>>(ypre, stats, lg, lb, out1);
}

// Round 12
// 990.720 us; speedup vs baseline: 1.0975x; 1.0975x over previous
//
#include <hip/hip_runtime.h>
#include <hip/hip_bf16.h>

#define BB 8
#define NN 4096
#define DD 64
#define SS 1024
#define KK 32
#define C1 64
#define C2 128

typedef unsigned int uint32;
typedef unsigned long long uint64;

constexpr int BSK = BB * SS * KK;   // 262144
constexpr int BS  = BB * SS;        // 8192

// ---- per-slot stats offsets (slot stride = 704 floats, 64 slots) ----
#define ST_S1_C1 0
#define ST_S2_C1 64
#define ST_S1_C2 128
#define ST_S2_C2 256
#define ST_S1_W0 384
#define ST_S2_W0 392
#define ST_S1_W1 400
#define ST_S2_W1 408
#define ST_S1_W2 416
#define ST_S2_W2 432
#define ST_S1_Y  448
#define ST_S2_Y  576
#define ST_STRIDE 704
#define N_SLOTS 64

#define PA_A_C1 0
#define PA_C_C1 64
#define PA_A_C2 128
#define PA_C_C2 256
#define PA_A_W0 384
#define PA_C_W0 392
#define PA_A_W1 400
#define PA_C_W1 408
#define PA_A_W2 416
#define PA_C_W2 432
// params floats [448, 704) are unused -> progress counters live there

// ------------------------------------------------------------------
// DPP cross-lane helpers (packed-key trick, see prior session notes)
// ------------------------------------------------------------------
#if __has_builtin(__builtin_amdgcn_update_dpp)
#define HAS_DPP 1
template <int CTRL>
__device__ __forceinline__ double dpp_f64(double x) {
    uint64 u = (uint64)__double_as_longlong(x);
    int lo = (int)(uint32)u, hi = (int)(uint32)(u >> 32);
    int lo2 = __builtin_amdgcn_update_dpp(lo, lo, CTRL, 0xf, 0xf, false);
    int hi2 = __builtin_amdgcn_update_dpp(hi, hi, CTRL, 0xf, 0xf, false);
    return __longlong_as_double((long long)(((uint64)(uint32)hi2 << 32) | (uint32)lo2));
}
__device__ __forceinline__ double wave_max_pack(double k) {
    k = fmax(k, dpp_f64<0x111>(k));
    k = fmax(k, dpp_f64<0x112>(k));
    k = fmax(k, dpp_f64<0x114>(k));
    k = fmax(k, dpp_f64<0x118>(k));
    k = fmax(k, dpp_f64<0x142>(k));
    k = fmax(k, dpp_f64<0x143>(k));
    return k;                          // lane 63 holds wave max
}
__device__ __forceinline__ double wave_min_pack(double k) {
    k = fmin(k, dpp_f64<0x111>(k));
    k = fmin(k, dpp_f64<0x112>(k));
    k = fmin(k, dpp_f64<0x114>(k));
    k = fmin(k, dpp_f64<0x118>(k));
    k = fmin(k, dpp_f64<0x142>(k));
    k = fmin(k, dpp_f64<0x143>(k));
    return k;                          // lane 63 holds wave min
}
__device__ __forceinline__ uint64 bcast63_u64(double k) {
#if __has_builtin(__builtin_amdgcn_readlane)
    uint64 u = (uint64)__double_as_longlong(k);
    int lo = __builtin_amdgcn_readlane((int)(uint32)u, 63);
    int hi = __builtin_amdgcn_readlane((int)(uint32)(u >> 32), 63);
    return ((uint64)(uint32)hi << 32) | (uint32)lo;
#else
    return (uint64)__double_as_longlong(__shfl(k, 63));
#endif
}
#define FPS_WRITER_LANE 63
template <int CTRL>
__device__ __forceinline__ float dpp_mov_f32(float x) {
    int r = __builtin_amdgcn_update_dpp(__float_as_int(x), __float_as_int(x),
                                        CTRL, 0xf, 0xf, false);
    return __int_as_float(r);
}
__device__ __forceinline__ float wave_sum_f32(float v) {
    v += dpp_mov_f32<0x111>(v);
    v += dpp_mov_f32<0x112>(v);
    v += dpp_mov_f32<0x114>(v);
    v += dpp_mov_f32<0x118>(v);
    v += dpp_mov_f32<0x142>(v);
    v += dpp_mov_f32<0x143>(v);
    return v;                          // lane 63 holds wave sum
}
#define LIN_WRITER 63
#else
#define HAS_DPP 0
__device__ __forceinline__ double wave_max_pack(double k) {
#pragma unroll
    for (int m = 32; m >= 1; m >>= 1) k = fmax(k, __shfl_xor(k, m));
    return k;
}
__device__ __forceinline__ double wave_min_pack(double k) {
#pragma unroll
    for (int m = 32; m >= 1; m >>= 1) k = fmin(k, __shfl_xor(k, m));
    return k;
}
__device__ __forceinline__ uint64 bcast63_u64(double k) {
    return (uint64)__double_as_longlong(k);
}
#define FPS_WRITER_LANE 0
__device__ __forceinline__ float wave_sum_f32(float v) {
#pragma unroll
    for (int m = 32; m >= 1; m >>= 1) v += __shfl_xor(v, m);
    return v;
}
#define LIN_WRITER 0
#endif

// exact RNE f32 -> bf16 bits
__device__ __forceinline__ uint32 bf16rne(float x) {
    uint32 u = __float_as_uint(x);
    return (u + 0x7fffu + ((u >> 16) & 1u)) >> 16;
}

// MFMA fragment types (guide-blessed)
typedef __attribute__((ext_vector_type(8))) short bf16x8;
typedef __attribute__((ext_vector_type(4))) float f32x4v;

// ------------------------------------------------------------------
// staging: gather 32 neighbors x 64 dims (bf16 -> fp32 LDS)
// ------------------------------------------------------------------
__device__ __forceinline__ void stage_pts(const __hip_bfloat16* __restrict__ ptsT,
                                          const int* __restrict__ nidx,
                                          int q, int b, int t, float* pts) {
    int k = t >> 3, d8 = t & 7;
    int nn = nidx[(size_t)q * KK + k];
    uint4 u = ((const uint4*)ptsT)[((size_t)b * NN + nn) * 8 + d8];
    float4 lo, hi;
    lo.x = __uint_as_float(u.x << 16); lo.y = __uint_as_float(u.x & 0xffff0000u);
    lo.z = __uint_as_float(u.y << 16); lo.w = __uint_as_float(u.y & 0xffff0000u);
    hi.x = __uint_as_float(u.z << 16); hi.y = __uint_as_float(u.z & 0xffff0000u);
    hi.z = __uint_as_float(u.w << 16); hi.w = __uint_as_float(u.w & 0xffff0000u);
    *(float4*)&pts[k * 64 + d8 * 8] = lo;
    *(float4*)&pts[k * 64 + d8 * 8 + 4] = hi;
}

// ------------------------------------------------------------------
// prep_fps_knn (r10 structure, measured 653us): blocks [0,8) FPS with
// streaming publish; [8,520) points transpose; [520,1592) weight
// transposes (+ MFMA-packed bf16 hi/lo w2 into the w2t buffer when
// pack_w2 — tier-2 never reads plain w2t); [1592,3640) kNN consumers.
// LDS padded to 82,048 B => 1 block/CU (FPS CUs exclusive).
// ------------------------------------------------------------------
__global__ __launch_bounds__(256) void prep_fps_knn(const float* __restrict__ points,
                                                    __hip_bfloat16* __restrict__ ptsT,
                                                    const float* __restrict__ c1_w,
                                                    const float* __restrict__ c2_w,
                                                    const float* __restrict__ lin_w,
                                                    float* __restrict__ w1t,
                                                    float* __restrict__ w2t,
                                                    __hip_bfloat16* __restrict__ linB,
                                                    const float* __restrict__ xyz,
                                                    float* __restrict__ new_xyz,
                                                    float* __restrict__ out0,
                                                    int* __restrict__ progress,
                                                    int* __restrict__ nidx,
                                                    float* __restrict__ offs,
                                                    int pack_w2) {
    __shared__ __align__(16) char smu[82048];   // >81,920 B => 1 block/CU
    int t = threadIdx.x;
    int blk = blockIdx.x;
    if (blk < 8) {
        // -------- FPS (exclusive CU) --------
        __builtin_amdgcn_s_setprio(3);
        float4* xyz4 = (float4*)smu;              // [NN] 65536 B
        int* hist = (int*)(smu + 65536);          // [SS] 4096 B
        double* slots = (double*)(smu + 69632);   // [2][4] 64 B
        int b = blk;
        int wv = t >> 6, lane = t & 63;
        const float* base = xyz + (size_t)b * 3 * NN;
        float px[16], py[16], pz[16], dl[16];
        uint32 lidx[16];
#pragma unroll
        for (int i = 0; i < 16; i++) {
            int n = t + 256 * i;
            px[i] = base[n];
            py[i] = base[NN + n];
            pz[i] = base[2 * NN + n];
            float4 v; v.x = px[i]; v.y = py[i]; v.z = pz[i]; v.w = 0.f;
            xyz4[n] = v;
            dl[i] = 1e10f;
            lidx[i] = (uint32)(NN - 1 - n);
        }
        if (t == 0) hist[0] = 0;
        __syncthreads();
        int far = 0;
        for (int step = 1; step < SS; step++) {
            int p = step & 1;
            float4 c = xyz4[far];                 // one b128 broadcast read
            float cx = c.x, cy = c.y, cz = c.z;
            double k0 = 0.0, k1 = 0.0, k2 = 0.0, k3 = 0.0;
#pragma unroll
            for (int i = 0; i < 16; i++) {
                // EXACT arithmetic (must match jax reference bit-for-bit)
                float dx = __fsub_rn(px[i], cx);
                float dy = __fsub_rn(py[i], cy);
                float dz = __fsub_rn(pz[i], cz);
                float d = __fadd_rn(__fadd_rn(__fmul_rn(dx, dx), __fmul_rn(dy, dy)),
                                    __fmul_rn(dz, dz));
                float nd = fminf(dl[i], d);
                dl[i] = nd;
                uint64 kbits = ((uint64)__float_as_uint(nd) << 32) | lidx[i];
                double kk = __longlong_as_double((long long)kbits);
                if ((i & 3) == 0) k0 = fmax(k0, kk);
                else if ((i & 3) == 1) k1 = fmax(k1, kk);
                else if ((i & 3) == 2) k2 = fmax(k2, kk);
                else k3 = fmax(k3, kk);
            }
            double kbest = fmax(fmax(k0, k1), fmax(k2, k3));
            kbest = wave_max_pack(kbest);
            if (lane == FPS_WRITER_LANE) slots[p * 4 + wv] = kbest;
            __syncthreads();
            double s0 = slots[p * 4 + 0], s1 = slots[p * 4 + 1];
            double s2 = slots[p * 4 + 2], s3 = slots[p * 4 + 3];
            double bk = fmax(fmax(s0, s1), fmax(s2, s3));
            uint64 kb = (uint64)__double_as_longlong(bk);
            int bbx = (NN - 1) - (int)(uint32)(kb & 0xffffffffull);
            far = bbx;
            if (t == 0) hist[step] = bbx;
            // streaming publish: every 32 steps, wave-0 lanes 0-31 push
            // entries [step-33, step-1) then lane 0 release-stores progress.
            if ((step & 31) == 1 && step > 32) {
                if (t < 32) {
                    int s2p = step - 33 + t;
                    int idx2 = hist[s2p];
                    float4 v2 = xyz4[idx2];
                    size_t qq = (size_t)(b * SS + s2p) * 3;
                    new_xyz[qq + 0] = v2.x;
                    new_xyz[qq + 1] = v2.y;
                    new_xyz[qq + 2] = v2.z;
                }
                if (t == 0)
                    __hip_atomic_store(&progress[b], step - 1, __ATOMIC_RELEASE,
                                       __HIP_MEMORY_SCOPE_AGENT);
            }
        }
        __syncthreads();
        // epilogue: coalesced output writes
        for (int s = t; s < SS; s += 256) {
            int idx = hist[s];
            float4 v = xyz4[idx];
            size_t q = (size_t)(b * SS + s);
            new_xyz[q * 3 + 0] = v.x;
            new_xyz[q * 3 + 1] = v.y;
            new_xyz[q * 3 + 2] = v.z;
            out0[(size_t)b * 3 * SS + 0 * SS + s] = v.x;
            out0[(size_t)b * 3 * SS + 1 * SS + s] = v.y;
            out0[(size_t)b * 3 * SS + 2 * SS + s] = v.z;
        }
        __threadfence();
        __syncthreads();
        if (t == 0)
            __hip_atomic_store(&progress[b], SS, __ATOMIC_RELEASE,
                               __HIP_MEMORY_SCOPE_AGENT);
        __builtin_amdgcn_s_setprio(0);
    } else if (blk < 520) {
        // -------- points transpose --------
        float (*tile)[65] = (float(*)[65])smu;
        int bb = blk - 8;
        int b = bb >> 6;
        int n0 = (bb & 63) * 64;
        for (int i = t; i < 4096; i += 256) {
            int d = i >> 6, n = i & 63;
            tile[d][n] = points[((size_t)b * DD + d) * NN + n0 + n];
        }
        __syncthreads();
        for (int i = t; i < 4096; i += 256) {
            int n = i >> 6, d = i & 63;
            ptsT[((size_t)b * NN + n0 + n) * DD + d] = __float2bfloat16(tile[d][n]);
        }
    } else if (blk < 1592) {
        // -------- weight transposes + lin_w -> bf16 --------
        int i = (blk - 520) * 256 + t;
        if (i < 4096) {
            int d = i >> 6, c = i & 63;
            w1t[d * 64 + c] = c1_w[c * 64 + d];
        }
        int j = i - 4096;
        if (j >= 0 && j < 8192) {
            if (!pack_w2) {
                int d = j >> 7, c = j & 127;
                w2t[d * 128 + c] = c2_w[c * 64 + d];
            } else {
                // MFMA B-fragment packed bf16 hi/lo layout into w2t bytes:
                // j = (((s*8+nf)*4+lg)*16+ln)*8+jj ; value = c2_w[c][d]
                int jj = j & 7, lnn = (j >> 3) & 15, lgg = (j >> 7) & 3;
                int nf = (j >> 9) & 7, s = (j >> 12) & 1;
                int d = s * 32 + lgg * 8 + jj;
                int c = nf * 16 + lnn;
                float v = c2_w[c * 64 + d];
                uint32 hb = bf16rne(v);
                float hif = __uint_as_float(hb << 16);
                uint32 lb2 = bf16rne(v - hif);
                unsigned short* w2p = (unsigned short*)w2t;
                w2p[j] = (unsigned short)hb;
                w2p[8192 + j] = (unsigned short)lb2;
            }
        }
        int l = i - 12288;
        if (l >= 0 && l < 262144) linB[l] = __float2bfloat16(lin_w[l]);
    } else {
        // -------- kNN consumer: one wave per query, interleaved map --------
        int cb = blk - 1592;                  // 0..2047
        int wv = t >> 6, lane = t & 63;
        int bq = cb & 7;                      // batch
        int pos = ((cb >> 3) << 2) + wv;      // position within batch
        int q = bq * SS + pos;                // global query
        int needed = pos + 1;
        while (__hip_atomic_load(&progress[bq], __ATOMIC_ACQUIRE,
                                 __HIP_MEMORY_SCOPE_AGENT) < needed)
            __builtin_amdgcn_s_sleep(32);
        const float* base = xyz + (size_t)bq * 3 * NN;
        float sx = new_xyz[(size_t)q * 3 + 0];
        float sy = new_xyz[(size_t)q * 3 + 1];
        float sz = new_xyz[(size_t)q * 3 + 2];
        float s2 = __fadd_rn(__fadd_rn(__fmul_rn(sx, sx), __fmul_rn(sy, sy)), __fmul_rn(sz, sz));
        float dl[64];
#pragma unroll
        for (int i = 0; i < 64; i++) {
            int n = i * 64 + lane;
            float x = base[n], y = base[NN + n], z = base[2 * NN + n];
            float d2 = __fadd_rn(__fadd_rn(__fmul_rn(x, x), __fmul_rn(y, y)), __fmul_rn(z, z));
            float dot = __fadd_rn(__fadd_rn(__fmul_rn(sx, x), __fmul_rn(sy, y)), __fmul_rn(sz, z));
            float v = __fmul_rn(-2.0f, dot);
            v = __fadd_rn(v, s2);
            v = __fadd_rn(v, d2);
            dl[i] = v;
        }
        const float MASKF = __uint_as_float(0x7F7FFFFFu);   // FLT_MAX
        unsigned long long excl = 0ull;
        for (int k = 0; k < KK; k++) {
            float best = MASKF;
            int bslot = 0;
#pragma unroll
            for (int i = 0; i < 64; i++) {
                bool ok = ((excl >> i) & 1ull) == 0ull;
                float v = ok ? dl[i] : MASKF;
                if (v < best) { best = v; bslot = i; }
            }
            uint64 kbits = ((uint64)__float_as_uint(best) << 32) |
                           (uint32)(bslot * 64 + lane);
            double kb = wave_min_pack(__longlong_as_double((long long)kbits));
            uint64 r = bcast63_u64(kb);
            int bi = (int)(uint32)(r & 0xffffffffull);
            if ((bi & 63) == lane) excl |= (1ull << (bi >> 6));
            if (lane == 0) {
                nidx[(size_t)q * KK + k] = bi;
                size_t oo = ((size_t)q * KK + k) * 3;
                offs[oo + 0] = __fsub_rn(base[bi], sx);
                offs[oo + 1] = __fsub_rn(base[NN + bi], sy);
                offs[oo + 2] = __fsub_rn(base[2 * NN + bi], sz);
            }
        }
    }
}

// ------------------------------------------------------------------
// pass A: conv1 stats + w0 stats; optional f1pre materialization
// ------------------------------------------------------------------
__global__ __launch_bounds__(256) void pass_a(const __hip_bfloat16* __restrict__ ptsT,
                                              const int* __restrict__ nidx,
                                              const float* __restrict__ offs,
                                              const float* __restrict__ w1t,
                                              const float* __restrict__ c1_b,
                                              const float* __restrict__ w0_w,
                                              const float* __restrict__ w0_b,
                                              float* __restrict__ stats,
                                              float* __restrict__ f1pre,
                                              int emit_f1) {
    __shared__ __align__(16) float pts[2048];
    __shared__ float red1[256], red2[256];
    int blk = blockIdx.x, t = threadIdx.x;
    int b = blk >> 10;
    int slot = blk & (N_SLOTS - 1);
    stage_pts(ptsT, nidx, blk, b, t, pts);
    __syncthreads();
    int c = t & 63, kg = t >> 6;
    float bias = c1_b[c];
    float acc[8];
#pragma unroll
    for (int j = 0; j < 8; j++) acc[j] = bias;
    for (int d4 = 0; d4 < 16; d4++) {
        float w0 = w1t[(4 * d4 + 0) * 64 + c];
        float w1v = w1t[(4 * d4 + 1) * 64 + c];
        float w2v = w1t[(4 * d4 + 2) * 64 + c];
        float w3 = w1t[(4 * d4 + 3) * 64 + c];
#pragma unroll
        for (int j = 0; j < 8; j++) {
            const float4 p = *(const float4*)&pts[(kg + 4 * j) * 64 + 4 * d4];
            acc[j] = fmaf(p.x, w0, acc[j]);
            acc[j] = fmaf(p.y, w1v, acc[j]);
            acc[j] = fmaf(p.z, w2v, acc[j]);
            acc[j] = fmaf(p.w, w3, acc[j]);
        }
    }
    if (emit_f1) {
#pragma unroll
        for (int j = 0; j < 8; j++)
            f1pre[(size_t)blk * 2048 + j * 256 + t] = acc[j];
    }
    float s1 = 0.f, s2 = 0.f;
#pragma unroll
    for (int j = 0; j < 8; j++) { s1 += acc[j]; s2 += acc[j] * acc[j]; }
    red1[t] = s1;
    red2[t] = s2;
    __syncthreads();
    if (t < 64) {
        atomicAdd(&stats[slot * ST_STRIDE + ST_S1_C1 + t],
                  red1[t] + red1[t + 64] + red1[t + 128] + red1[t + 192]);
        atomicAdd(&stats[slot * ST_STRIDE + ST_S2_C1 + t],
                  red2[t] + red2[t + 64] + red2[t + 128] + red2[t + 192]);
    }
    int k0 = t >> 3, c0 = t & 7;
    size_t oo = ((size_t)blk * KK + k0) * 3;
    float h = w0_b[c0];
    h = fmaf(offs[oo + 0], w0_w[c0 * 3 + 0], h);
    h = fmaf(offs[oo + 1], w0_w[c0 * 3 + 1], h);
    h = fmaf(offs[oo + 2], w0_w[c0 * 3 + 2], h);
    __syncthreads();
    red1[t] = h;
    red2[t] = h * h;
    __syncthreads();
    if (t < 8) {
        float a = 0.f, q = 0.f;
        for (int j = t; j < 256; j += 8) { a += red1[j]; q += red2[j]; }
        atomicAdd(&stats[slot * ST_STRIDE + ST_S1_W0 + t], a);
        atomicAdd(&stats[slot * ST_STRIDE + ST_S2_W0 + t], q);
    }
}

// ------------------------------------------------------------------
// finalize BN(s) from slotted stats
// ------------------------------------------------------------------
__device__ __forceinline__ void fin_one(const float* stats, float* params,
                                        const float* g, const float* be,
                                        int s1o, int s2o, int ao, int co,
                                        int nch, float inv, int t) {
    if (t < nch) {
        float s1 = 0.f, s2 = 0.f;
        for (int s = 0; s < N_SLOTS; s++) {
            s1 += stats[s * ST_STRIDE + s1o + t];
            s2 += stats[s * ST_STRIDE + s2o + t];
        }
        float m = s1 * inv;
        float v = s2 * inv - m * m;
        float a = g[t] * rsqrtf(v + 1e-5f);
        params[ao + t] = a;
        params[co + t] = be[t] - m * a;
    }
}

__global__ void finalize_bn(const float* __restrict__ stats, float* __restrict__ params,
                            const float* __restrict__ g, const float* __restrict__ be,
                            int s1o, int s2o, int ao, int co, int nch, float inv) {
    fin_one(stats, params, g, be, s1o, s2o, ao, co, nch, inv, threadIdx.x);
}

__global__ void finalize_two(const float* __restrict__ stats, float* __restrict__ params,
                             const float* __restrict__ gA, const float* __restrict__ beA,
                             int s1A, int s2A, int aA, int cA, int nA, float invA,
                             const float* __restrict__ gB, const float* __restrict__ beB,
                             int s1B, int s2B, int aB, int cB, int nB, float invB) {
    if (blockIdx.x == 0)
        fin_one(stats, params, gA, beA, s1A, s2A, aA, cA, nA, invA, threadIdx.x);
    else
        fin_one(stats, params, gB, beB, s1B, s2B, aB, cB, nB, invB, threadIdx.x);
}

// ------------------------------------------------------------------
// pass B (tier-1 fallback): conv1 recompute + bn1relu -> f1; conv2
// stats; w1 stats (uses PLAIN w2t — only valid when !pack_w2)
// ------------------------------------------------------------------
__global__ __launch_bounds__(256) void pass_b(const __hip_bfloat16* __restrict__ ptsT,
                                              const int* __restrict__ nidx,
                                              const float* __restrict__ offs,
                                              const float* __restrict__ w1t,
                                              const float* __restrict__ c1_b,
                                              const float* __restrict__ w2t,
                                              const float* __restrict__ c2_b,
                                              const float* __restrict__ w0_w,
                                              const float* __restrict__ w0_b,
                                              const float* __restrict__ w1_w,
                                              const float* __restrict__ w1_b,
                                              const float* __restrict__ params,
                                              float* __restrict__ stats) {
    __shared__ __align__(16) float pts[2048];
    __shared__ __align__(16) float f1[2048];
    __shared__ float red1[256], red2[256];
    int blk = blockIdx.x, t = threadIdx.x;
    int b = blk >> 10;
    int slot = blk & (N_SLOTS - 1);
    stage_pts(ptsT, nidx, blk, b, t, pts);
    __syncthreads();
    {
        int c = t & 63, kg = t >> 6;
        float a1 = params[PA_A_C1 + c], cc1 = params[PA_C_C1 + c], bias = c1_b[c];
        float acc[8];
#pragma unroll
        for (int j = 0; j < 8; j++) acc[j] = bias;
        for (int d4 = 0; d4 < 16; d4++) {
            float w0 = w1t[(4 * d4 + 0) * 64 + c];
            float w1v = w1t[(4 * d4 + 1) * 64 + c];
            float w2v = w1t[(4 * d4 + 2) * 64 + c];
            float w3 = w1t[(4 * d4 + 3) * 64 + c];
#pragma unroll
            for (int j = 0; j < 8; j++) {
                const float4 p = *(const float4*)&pts[(kg + 4 * j) * 64 + 4 * d4];
                acc[j] = fmaf(p.x, w0, acc[j]);
                acc[j] = fmaf(p.y, w1v, acc[j]);
                acc[j] = fmaf(p.z, w2v, acc[j]);
                acc[j] = fmaf(p.w, w3, acc[j]);
            }
        }
#pragma unroll
        for (int j = 0; j < 8; j++)
            f1[(kg + 4 * j) * 64 + c] = fmaxf(fmaf(acc[j], a1, cc1), 0.f);
    }
    __syncthreads();
    {
        int c = t & 127, kg = t >> 7;
        float bias = c2_b[c];
        float acc[16];
#pragma unroll
        for (int j = 0; j < 16; j++) acc[j] = bias;
        for (int d4 = 0; d4 < 16; d4++) {
            float w0 = w2t[(4 * d4 + 0) * 128 + c];
            float w1v = w2t[(4 * d4 + 1) * 128 + c];
            float w2v = w2t[(4 * d4 + 2) * 128 + c];
            float w3 = w2t[(4 * d4 + 3) * 128 + c];
#pragma unroll
            for (int j = 0; j < 16; j++) {
                const float4 p = *(const float4*)&f1[(kg + 2 * j) * 64 + 4 * d4];
                acc[j] = fmaf(p.x, w0, acc[j]);
                acc[j] = fmaf(p.y, w1v, acc[j]);
                acc[j] = fmaf(p.z, w2v, acc[j]);
                acc[j] = fmaf(p.w, w3, acc[j]);
            }
        }
        float s1 = 0.f, s2 = 0.f;
#pragma unroll
        for (int j = 0; j < 16; j++) { s1 += acc[j]; s2 += acc[j] * acc[j]; }
        red1[t] = s1;
        red2[t] = s2;
    }
    __syncthreads();
    if (t < 128) {
        atomicAdd(&stats[slot * ST_STRIDE + ST_S1_C2 + t], red1[t] + red1[t + 128]);
        atomicAdd(&stats[slot * ST_STRIDE + ST_S2_C2 + t], red2[t] + red2[t + 128]);
    }
    {
        int k0 = t >> 3, c0 = t & 7;
        size_t oo = ((size_t)blk * KK + k0) * 3;
        float o0 = offs[oo], o1 = offs[oo + 1], o2 = offs[oo + 2];
        float h0[8];
#pragma unroll
        for (int j = 0; j < 8; j++) {
            float hh = w0_b[j];
            hh = fmaf(o0, w0_w[j * 3 + 0], hh);
            hh = fmaf(o1, w0_w[j * 3 + 1], hh);
            hh = fmaf(o2, w0_w[j * 3 + 2], hh);
            h0[j] = fmaxf(fmaf(hh, params[PA_A_W0 + j], params[PA_C_W0 + j]), 0.f);
        }
        float h = w1_b[c0];
#pragma unroll
        for (int j = 0; j < 8; j++) h = fmaf(h0[j], w1_w[c0 * 8 + j], h);
        __syncthreads();
        red1[t] = h;
        red2[t] = h * h;
        __syncthreads();
        if (t < 8) {
            float a = 0.f, q = 0.f;
            for (int j = t; j < 256; j += 8) { a += red1[j]; q += red2[j]; }
            atomicAdd(&stats[slot * ST_STRIDE + ST_S1_W1 + t], a);
            atomicAdd(&stats[slot * ST_STRIDE + ST_S2_W1 + t], q);
        }
    }
}

// ------------------------------------------------------------------
// pass B2 (tier-2, MFMA): read f1pre, bn1relu -> bf16 hi/lo LDS;
// conv2 via mfma_f32_16x16x32_bf16 with 3-product hi/lo split
// (AhBh + AlBh + AhBl; AlBl ~2^-18 dropped) against pre-packed w2;
// f2pre + c2 stats from fragments; w1 stats unchanged.
// ------------------------------------------------------------------
__global__ __launch_bounds__(256) void pass_b2(const float* __restrict__ f1pre,
                                               const float* __restrict__ offs,
                                               const unsigned short* __restrict__ w2pack,
                                               const float* __restrict__ c2_b,
                                               const float* __restrict__ w0_w,
                                               const float* __restrict__ w0_b,
                                               const float* __restrict__ w1_w,
                                               const float* __restrict__ w1_b,
                                               const float* __restrict__ params,
                                               float* __restrict__ stats,
                                               float* __restrict__ f2pre) {
    __shared__ __align__(16) unsigned short f1h[32 * 72];
    __shared__ __align__(16) unsigned short f1l[32 * 72];
    __shared__ float red1[256], red2[256];
    int blk = blockIdx.x, t = threadIdx.x;
    int slot = blk & (N_SLOTS - 1);
    // bn1relu + hi/lo bf16 split into padded LDS tiles
    {
        int c = t & 63;
        float a1 = params[PA_A_C1 + c], cc1 = params[PA_C_C1 + c];
#pragma unroll
        for (int i = 0; i < 8; i++) {
            int e = i * 256 + t;
            float v = f1pre[(size_t)blk * 2048 + e];
            float f = fmaxf(fmaf(v, a1, cc1), 0.f);
            int k = e >> 6, d = e & 63;
            uint32 hb = bf16rne(f);
            f1h[k * 72 + d] = (unsigned short)hb;
            f1l[k * 72 + d] = (unsigned short)bf16rne(f - __uint_as_float(hb << 16));
        }
    }
    __syncthreads();
    int lane = t & 63, w = t >> 6;
    int lg = lane >> 4, ln = lane & 15;
    f32x4v acc00 = {0.f, 0.f, 0.f, 0.f};   // mf0, nfi0
    f32x4v acc01 = {0.f, 0.f, 0.f, 0.f};   // mf0, nfi1
    f32x4v acc10 = {0.f, 0.f, 0.f, 0.f};   // mf1, nfi0
    f32x4v acc11 = {0.f, 0.f, 0.f, 0.f};   // mf1, nfi1
#pragma unroll
    for (int s = 0; s < 2; s++) {
        int ao = s * 32 + lg * 8;
        bf16x8 ah0 = *(const bf16x8*)&f1h[(ln) * 72 + ao];
        bf16x8 ah1 = *(const bf16x8*)&f1h[(16 + ln) * 72 + ao];
        bf16x8 al0 = *(const bf16x8*)&f1l[(ln) * 72 + ao];
        bf16x8 al1 = *(const bf16x8*)&f1l[(16 + ln) * 72 + ao];
        int nf0 = w * 2, nf1 = w * 2 + 1;
        int b0off = (((s * 8 + nf0) * 4 + lg) * 16 + ln) * 8;
        int b1off = (((s * 8 + nf1) * 4 + lg) * 16 + ln) * 8;
        bf16x8 bh0 = *(const bf16x8*)&w2pack[b0off];
        bf16x8 bl0 = *(const bf16x8*)&w2pack[8192 + b0off];
        bf16x8 bh1 = *(const bf16x8*)&w2pack[b1off];
        bf16x8 bl1 = *(const bf16x8*)&w2pack[8192 + b1off];
        acc00 = __builtin_amdgcn_mfma_f32_16x16x32_bf16(ah0, bh0, acc00, 0, 0, 0);
        acc00 = __builtin_amdgcn_mfma_f32_16x16x32_bf16(al0, bh0, acc00, 0, 0, 0);
        acc00 = __builtin_amdgcn_mfma_f32_16x16x32_bf16(ah0, bl0, acc00, 0, 0, 0);
        acc01 = __builtin_amdgcn_mfma_f32_16x16x32_bf16(ah0, bh1, acc01, 0, 0, 0);
        acc01 = __builtin_amdgcn_mfma_f32_16x16x32_bf16(al0, bh1, acc01, 0, 0, 0);
        acc01 = __builtin_amdgcn_mfma_f32_16x16x32_bf16(ah0, bl1, acc01, 0, 0, 0);
        acc10 = __builtin_amdgcn_mfma_f32_16x16x32_bf16(ah1, bh0, acc10, 0, 0, 0);
        acc10 = __builtin_amdgcn_mfma_f32_16x16x32_bf16(al1, bh0, acc10, 0, 0, 0);
        acc10 = __builtin_amdgcn_mfma_f32_16x16x32_bf16(ah1, bl0, acc10, 0, 0, 0);
        acc11 = __builtin_amdgcn_mfma_f32_16x16x32_bf16(ah1, bh1, acc11, 0, 0, 0);
        acc11 = __builtin_amdgcn_mfma_f32_16x16x32_bf16(al1, bh1, acc11, 0, 0, 0);
        acc11 = __builtin_amdgcn_mfma_f32_16x16x32_bf16(ah1, bl1, acc11, 0, 0, 0);
    }
    // epilogue: +bias, write f2pre [k*128+c], c2 stats via shfl reduce
    {
        int c0 = w * 32 + ln;
        int c1c = w * 32 + 16 + ln;
        float b0 = c2_b[c0], b1 = c2_b[c1c];
        float p10 = 0.f, p20 = 0.f, p11 = 0.f, p21 = 0.f;
#pragma unroll
        for (int r = 0; r < 4; r++) {
            int k0 = lg * 4 + r;          // C/D row = (lane>>4)*4 + reg
            int k1 = 16 + lg * 4 + r;
            float v00 = acc00[r] + b0;
            float v01 = acc01[r] + b1;
            float v10 = acc10[r] + b0;
            float v11 = acc11[r] + b1;
            f2pre[(size_t)blk * 4096 + k0 * 128 + c0]  = v00;
            f2pre[(size_t)blk * 4096 + k0 * 128 + c1c] = v01;
            f2pre[(size_t)blk * 4096 + k1 * 128 + c0]  = v10;
            f2pre[(size_t)blk * 4096 + k1 * 128 + c1c] = v11;
            p10 += v00 + v10; p20 += v00 * v00 + v10 * v10;
            p11 += v01 + v11; p21 += v01 * v01 + v11 * v11;
        }
        p10 += __shfl_xor(p10, 16); p10 += __shfl_xor(p10, 32);
        p20 += __shfl_xor(p20, 16); p20 += __shfl_xor(p20, 32);
        p11 += __shfl_xor(p11, 16); p11 += __shfl_xor(p11, 32);
        p21 += __shfl_xor(p21, 16); p21 += __shfl_xor(p21, 32);
        if (lg == 0) {
            atomicAdd(&stats[slot * ST_STRIDE + ST_S1_C2 + c0], p10);
            atomicAdd(&stats[slot * ST_STRIDE + ST_S2_C2 + c0], p20);
            atomicAdd(&stats[slot * ST_STRIDE + ST_S1_C2 + c1c], p11);
            atomicAdd(&stats[slot * ST_STRIDE + ST_S2_C2 + c1c], p21);
        }
    }
    // w1 stats (unchanged)
    {
        int k0 = t >> 3, c0 = t & 7;
        size_t oo = ((size_t)blk * KK + k0) * 3;
        float o0 = offs[oo], o1 = offs[oo + 1], o2 = offs[oo + 2];
        float h0[8];
#pragma unroll
        for (int j = 0; j < 8; j++) {
            float hh = w0_b[j];
            hh = fmaf(o0, w0_w[j * 3 + 0], hh);
            hh = fmaf(o1, w0_w[j * 3 + 1], hh);
            hh = fmaf(o2, w0_w[j * 3 + 2], hh);
            h0[j] = fmaxf(fmaf(hh, params[PA_A_W0 + j], params[PA_C_W0 + j]), 0.f);
        }
        float h = w1_b[c0];
#pragma unroll
        for (int j = 0; j < 8; j++) h = fmaf(h0[j], w1_w[c0 * 8 + j], h);
        red1[t] = h;
        red2[t] = h * h;
        __syncthreads();
        if (t < 8) {
            float a = 0.f, q = 0.f;
            for (int j = t; j < 256; j += 8) { a += red1[j]; q += red2[j]; }
            atomicAdd(&stats[slot * ST_STRIDE + ST_S1_W1 + t], a);
            atomicAdd(&stats[slot * ST_STRIDE + ST_S2_W1 + t], q);
        }
    }
}

// ------------------------------------------------------------------
// w2 stats (unchanged)
// ------------------------------------------------------------------
__global__ __launch_bounds__(256) void pass_w2(const float* __restrict__ offs,
                                               const float* __restrict__ w0_w,
                                               const float* __restrict__ w0_b,
                                               const float* __restrict__ w1_w,
                                               const float* __restrict__ w1_b,
                                               const float* __restrict__ w2_w,
                                               const float* __restrict__ w2_b,
                                               const float* __restrict__ params,
                                               float* __restrict__ stats) {
    int i = blockIdx.x * 256 + threadIdx.x;
    int slot = blockIdx.x & (N_SLOTS - 1);
    size_t oo = (size_t)i * 3;
    float o0 = offs[oo], o1 = offs[oo + 1], o2 = offs[oo + 2];
    float h0[8], h1[8];
#pragma unroll
    for (int j = 0; j < 8; j++) {
        float hh = w0_b[j];
        hh = fmaf(o0, w0_w[j * 3 + 0], hh);
        hh = fmaf(o1, w0_w[j * 3 + 1], hh);
        hh = fmaf(o2, w0_w[j * 3 + 2], hh);
        h0[j] = fmaxf(fmaf(hh, params[PA_A_W0 + j], params[PA_C_W0 + j]), 0.f);
    }
#pragma unroll
    for (int j = 0; j < 8; j++) {
        float hh = w1_b[j];
#pragma unroll
        for (int q = 0; q < 8; q++) hh = fmaf(h0[q], w1_w[j * 8 + q], hh);
        h1[j] = fmaxf(fmaf(hh, params[PA_A_W1 + j], params[PA_C_W1 + j]), 0.f);
    }
#pragma unroll
    for (int c = 0; c < 16; c++) {
        float h = w2_b[c];
#pragma unroll
        for (int q = 0; q < 8; q++) h = fmaf(h1[q], w2_w[c * 8 + q], h);
        float v = wave_sum_f32(h);
        float s = wave_sum_f32(h * h);
        if ((threadIdx.x & 63) == LIN_WRITER) {
            atomicAdd(&stats[slot * ST_STRIDE + ST_S1_W2 + c], v);
            atomicAdd(&stats[slot * ST_STRIDE + ST_S2_W2 + c], s);
        }
    }
}

// ------------------------------------------------------------------
// weightnet device helper (shared by tails)
// ------------------------------------------------------------------
__device__ __forceinline__ void weightnet_to_lds(const float* __restrict__ offs,
                                                 const float* __restrict__ w0_w,
                                                 const float* __restrict__ w0_b,
                                                 const float* __restrict__ w1_w,
                                                 const float* __restrict__ w1_b,
                                                 const float* __restrict__ w2_w,
                                                 const float* __restrict__ w2_b,
                                                 const float* __restrict__ params,
                                                 int blk, int t, float* wg) {
    for (int idx = t; idx < KK * 16; idx += 256) {
        int k = idx >> 4, cw = idx & 15;
        size_t oo = ((size_t)blk * KK + k) * 3;
        float o0 = offs[oo], o1 = offs[oo + 1], o2 = offs[oo + 2];
        float h0[8], h1[8];
#pragma unroll
        for (int j = 0; j < 8; j++) {
            float hh = w0_b[j];
            hh = fmaf(o0, w0_w[j * 3 + 0], hh);
            hh = fmaf(o1, w0_w[j * 3 + 1], hh);
            hh = fmaf(o2, w0_w[j * 3 + 2], hh);
            h0[j] = fmaxf(fmaf(hh, params[PA_A_W0 + j], params[PA_C_W0 + j]), 0.f);
        }
#pragma unroll
        for (int j = 0; j < 8; j++) {
            float hh = w1_b[j];
#pragma unroll
            for (int q = 0; q < 8; q++) hh = fmaf(h0[q], w1_w[j * 8 + q], hh);
            h1[j] = fmaxf(fmaf(hh, params[PA_A_W1 + j], params[PA_C_W1 + j]), 0.f);
        }
        float h = w2_b[cw];
#pragma unroll
        for (int q = 0; q < 8; q++) h = fmaf(h1[q], w2_w[cw * 8 + q], h);
        wg[idx] = fmaxf(fmaf(h, params[PA_A_W2 + cw], params[PA_C_W2 + cw]), 0.f);
    }
}

// ------------------------------------------------------------------
// tail_nl2 (tier-2): read f2pre + bn2relu -> LDS; weightnet; einsum;
// feats -> global.
// ------------------------------------------------------------------
__global__ __launch_bounds__(256) void tail_nl2(const float* __restrict__ f2pre,
                                                const float* __restrict__ offs,
                                                const float* __restrict__ w0_w,
                                                const float* __restrict__ w0_b,
                                                const float* __restrict__ w1_w,
                                                const float* __restrict__ w1_b,
                                                const float* __restrict__ w2_w,
                                                const float* __restrict__ w2_b,
                                                const float* __restrict__ params,
                                                float* __restrict__ featsF) {
    __shared__ __align__(16) float sm[6656];
    float* f2    = sm;            // [4096]
    float* wg    = sm + 4096;     // [512]
    float* feats = sm + 4608;     // [2048]
    int blk = blockIdx.x, t = threadIdx.x;
    weightnet_to_lds(offs, w0_w, w0_b, w1_w, w1_b, w2_w, w2_b, params, blk, t, wg);
    {
        int c = t & 127;
        float a2 = params[PA_A_C2 + c], cc2 = params[PA_C_C2 + c];
#pragma unroll
        for (int i = 0; i < 16; i++) {
            float v = f2pre[(size_t)blk * 4096 + i * 256 + t];
            f2[i * 256 + t] = fmaxf(fmaf(v, a2, cc2), 0.f);
        }
    }
    __syncthreads();
    {
        int cc = t & 127, wh = t >> 7;
        float acc[8];
#pragma unroll
        for (int i = 0; i < 8; i++) acc[i] = 0.f;
        for (int k = 0; k < KK; k++) {
            float fv = f2[k * 128 + cc];
            const float4 wa = *(const float4*)&wg[k * 16 + 8 * wh];
            const float4 wb = *(const float4*)&wg[k * 16 + 8 * wh + 4];
            acc[0] = fmaf(fv, wa.x, acc[0]);
            acc[1] = fmaf(fv, wa.y, acc[1]);
            acc[2] = fmaf(fv, wa.z, acc[2]);
            acc[3] = fmaf(fv, wa.w, acc[3]);
            acc[4] = fmaf(fv, wb.x, acc[4]);
            acc[5] = fmaf(fv, wb.y, acc[5]);
            acc[6] = fmaf(fv, wb.z, acc[6]);
            acc[7] = fmaf(fv, wb.w, acc[7]);
        }
        *(float4*)&feats[cc * 16 + 8 * wh]     = *(float4*)&acc[0];
        *(float4*)&feats[cc * 16 + 8 * wh + 4] = *(float4*)&acc[4];
    }
    __syncthreads();
#pragma unroll
    for (int i = 0; i < 8; i++)
        featsF[(size_t)blk * 2048 + i * 256 + t] = feats[i * 256 + t];
}

// ------------------------------------------------------------------
// fused_tail_nl (tier-1): full recompute tail (plain w2t)
// ------------------------------------------------------------------
__global__ __launch_bounds__(256) void fused_tail_nl(
        const __hip_bfloat16* __restrict__ ptsT, const int* __restrict__ nidx,
        const float* __restrict__ offs,
        const float* __restrict__ w1t, const float* __restrict__ c1_b,
        const float* __restrict__ w2t, const float* __restrict__ c2_b,
        const float* __restrict__ w0_w, const float* __restrict__ w0_b,
        const float* __restrict__ w1_w, const float* __restrict__ w1_b,
        const float* __restrict__ w2_w, const float* __restrict__ w2_b,
        const float* __restrict__ params, float* __restrict__ featsF) {
    __shared__ __align__(16) float sm[8704];
    float* pts   = sm;
    float* f1    = sm + 2048;
    float* f2    = sm + 4096;
    float* wg    = sm + 8192;
    int blk = blockIdx.x, t = threadIdx.x;
    int b = blk >> 10;
    stage_pts(ptsT, nidx, blk, b, t, pts);
    weightnet_to_lds(offs, w0_w, w0_b, w1_w, w1_b, w2_w, w2_b, params, blk, t, wg);
    __syncthreads();
    {
        int c = t & 63, kg = t >> 6;
        float a1 = params[PA_A_C1 + c], cc1 = params[PA_C_C1 + c], bias = c1_b[c];
        float acc[8];
#pragma unroll
        for (int j = 0; j < 8; j++) acc[j] = bias;
        for (int d4 = 0; d4 < 16; d4++) {
            float w0 = w1t[(4 * d4 + 0) * 64 + c];
            float w1v = w1t[(4 * d4 + 1) * 64 + c];
            float w2v = w1t[(4 * d4 + 2) * 64 + c];
            float w3 = w1t[(4 * d4 + 3) * 64 + c];
#pragma unroll
            for (int j = 0; j < 8; j++) {
                const float4 p = *(const float4*)&pts[(kg + 4 * j) * 64 + 4 * d4];
                acc[j] = fmaf(p.x, w0, acc[j]);
                acc[j] = fmaf(p.y, w1v, acc[j]);
                acc[j] = fmaf(p.z, w2v, acc[j]);
                acc[j] = fmaf(p.w, w3, acc[j]);
            }
        }
#pragma unroll
        for (int j = 0; j < 8; j++)
            f1[(kg + 4 * j) * 64 + c] = fmaxf(fmaf(acc[j], a1, cc1), 0.f);
    }
    __syncthreads();
    {
        int c = t & 127, kg = t >> 7;
        float a2 = params[PA_A_C2 + c], cc2 = params[PA_C_C2 + c], bias = c2_b[c];
        float acc[16];
#pragma unroll
        for (int j = 0; j < 16; j++) acc[j] = bias;
        for (int d4 = 0; d4 < 16; d4++) {
            float w0 = w2t[(4 * d4 + 0) * 128 + c];
            float w1v = w2t[(4 * d4 + 1) * 128 + c];
            float w2v = w2t[(4 * d4 + 2) * 128 + c];
            float w3 = w2t[(4 * d4 + 3) * 128 + c];
#pragma unroll
            for (int j = 0; j < 16; j++) {
                const float4 p = *(const float4*)&f1[(kg + 2 * j) * 64 + 4 * d4];
                acc[j] = fmaf(p.x, w0, acc[j]);
                acc[j] = fmaf(p.y, w1v, acc[j]);
                acc[j] = fmaf(p.z, w2v, acc[j]);
                acc[j] = fmaf(p.w, w3, acc[j]);
            }
        }
#pragma unroll
        for (int j = 0; j < 16; j++)
            f2[(kg + 2 * j) * 128 + c] = fmaxf(fmaf(acc[j], a2, cc2), 0.f);
    }
    __syncthreads();
    {
        int cc = t & 127, wh = t >> 7;
        float acc[8];
#pragma unroll
        for (int i = 0; i < 8; i++) acc[i] = 0.f;
        for (int k = 0; k < KK; k++) {
            float fv = f2[k * 128 + cc];
            const float4 wa = *(const float4*)&wg[k * 16 + 8 * wh];
            const float4 wb = *(const float4*)&wg[k * 16 + 8 * wh + 4];
            acc[0] = fmaf(fv, wa.x, acc[0]);
            acc[1] = fmaf(fv, wa.y, acc[1]);
            acc[2] = fmaf(fv, wa.z, acc[2]);
            acc[3] = fmaf(fv, wa.w, acc[3]);
            acc[4] = fmaf(fv, wb.x, acc[4]);
            acc[5] = fmaf(fv, wb.y, acc[5]);
            acc[6] = fmaf(fv, wb.z, acc[6]);
            acc[7] = fmaf(fv, wb.w, acc[7]);
        }
        *(float4*)&pts[cc * 16 + 8 * wh]     = *(float4*)&acc[0];
        *(float4*)&pts[cc * 16 + 8 * wh + 4] = *(float4*)&acc[4];
    }
    __syncthreads();
#pragma unroll
    for (int i = 0; i < 8; i++)
        featsF[(size_t)blk * 2048 + i * 256 + t] = sm[i * 256 + t];
}

// ------------------------------------------------------------------
// linear_mm16: Y = feats . linB^T + lin_b via MFMA hi/lo bf16 split.
// ------------------------------------------------------------------
__global__ __launch_bounds__(256) void linear_mm16(const float* __restrict__ featsF,
                                                   const __hip_bfloat16* __restrict__ linB,
                                                   const float* __restrict__ lin_b,
                                                   float* __restrict__ stats,
                                                   float* __restrict__ ypre) {
    __shared__ __align__(16) unsigned short Ah[2][16 * 72];
    __shared__ __align__(16) unsigned short Al[2][16 * 72];
    __shared__ __align__(16) unsigned short Bsm[2][128 * 72];
    int t = threadIdx.x;
    int q0 = blockIdx.x * 16;
    int slot = blockIdx.x & (N_SLOTS - 1);
    int qa = t >> 4, pa = t & 15;
    int ob = t >> 1, pb = t & 1;
    int lane = t & 63, w = t >> 6;
    int lg = lane >> 4, ln = lane & 15;
    int qb_base = q0 + lg * 4;

    f32x4v acc0 = {0.f, 0.f, 0.f, 0.f};
    f32x4v acc1 = {0.f, 0.f, 0.f, 0.f};

    const uint4* gA0 = (const uint4*)(featsF + (size_t)(q0 + qa) * 2048);
    const uint4* gB0 = (const uint4*)(linB + (size_t)ob * 2048);

    uint4 ra, rb0, rb1, rb2, rb3;
    ra  = gA0[pa];
    rb0 = gB0[pb * 4 + 0];
    rb1 = gB0[pb * 4 + 1];
    rb2 = gB0[pb * 4 + 2];
    rb3 = gB0[pb * 4 + 3];

    for (int kc = 0; kc < 32; kc++) {
        int buf = kc & 1;
        {
            float f0 = __uint_as_float(ra.x), f1v = __uint_as_float(ra.y);
            float f2v = __uint_as_float(ra.z), f3 = __uint_as_float(ra.w);
            uint32 h0 = bf16rne(f0), h1 = bf16rne(f1v), h2 = bf16rne(f2v), h3 = bf16rne(f3);
            uint2 hv;
            hv.x = h0 | (h1 << 16); hv.y = h2 | (h3 << 16);
            *(uint2*)&Ah[buf][qa * 72 + pa * 4] = hv;
            uint32 l0 = bf16rne(f0 - __uint_as_float(h0 << 16));
            uint32 l1 = bf16rne(f1v - __uint_as_float(h1 << 16));
            uint32 l2 = bf16rne(f2v - __uint_as_float(h2 << 16));
            uint32 l3 = bf16rne(f3 - __uint_as_float(h3 << 16));
            uint2 lv;
            lv.x = l0 | (l1 << 16); lv.y = l2 | (l3 << 16);
            *(uint2*)&Al[buf][qa * 72 + pa * 4] = lv;
            *(uint4*)&Bsm[buf][ob * 72 + pb * 32 + 0]  = rb0;
            *(uint4*)&Bsm[buf][ob * 72 + pb * 32 + 8]  = rb1;
            *(uint4*)&Bsm[buf][ob * 72 + pb * 32 + 16] = rb2;
            *(uint4*)&Bsm[buf][ob * 72 + pb * 32 + 24] = rb3;
        }
        __syncthreads();
        if (kc + 1 < 32) {
            ra  = gA0[(kc + 1) * 16 + pa];
            rb0 = gB0[(kc + 1) * 8 + pb * 4 + 0];
            rb1 = gB0[(kc + 1) * 8 + pb * 4 + 1];
            rb2 = gB0[(kc + 1) * 8 + pb * 4 + 2];
            rb3 = gB0[(kc + 1) * 8 + pb * 4 + 3];
        }
#pragma unroll
        for (int s = 0; s < 2; s++) {
            int ko = s * 32 + lg * 8;
            bf16x8 ah = *(const bf16x8*)&Ah[buf][ln * 72 + ko];
            bf16x8 al = *(const bf16x8*)&Al[buf][ln * 72 + ko];
            bf16x8 b0 = *(const bf16x8*)&Bsm[buf][(w * 32 + 0  + ln) * 72 + ko];
            bf16x8 b1 = *(const bf16x8*)&Bsm[buf][(w * 32 + 16 + ln) * 72 + ko];
            acc0 = __builtin_amdgcn_mfma_f32_16x16x32_bf16(ah, b0, acc0, 0, 0, 0);
            acc0 = __builtin_amdgcn_mfma_f32_16x16x32_bf16(al, b0, acc0, 0, 0, 0);
            acc1 = __builtin_amdgcn_mfma_f32_16x16x32_bf16(ah, b1, acc1, 0, 0, 0);
            acc1 = __builtin_amdgcn_mfma_f32_16x16x32_bf16(al, b1, acc1, 0, 0, 0);
        }
    }
    {
        int o0 = w * 32 + 0  + ln;
        int o1 = w * 32 + 16 + ln;
        float lb0 = lin_b[o0], lb1 = lin_b[o1];
        float s1a = 0.f, s2a = 0.f, s1b = 0.f, s2b = 0.f;
#pragma unroll
        for (int r = 0; r < 4; r++) {
            size_t qrow = (size_t)(qb_base + r) * 128;
            float y0 = acc0[r] + lb0;
            float y1 = acc1[r] + lb1;
            ypre[qrow + o0] = y0;
            ypre[qrow + o1] = y1;
            s1a += y0; s2a += y0 * y0;
            s1b += y1; s2b += y1 * y1;
        }
        atomicAdd(&stats[slot * ST_STRIDE + ST_S1_Y + o0], s1a);
        atomicAdd(&stats[slot * ST_STRIDE + ST_S2_Y + o0], s2a);
        atomicAdd(&stats[slot * ST_STRIDE + ST_S1_Y + o1], s1b);
        atomicAdd(&stats[slot * ST_STRIDE + ST_S2_Y + o1], s2b);
    }
}

// ------------------------------------------------------------------
// final BN + relu + tiled transpose write to out1 [B,128,S]
// ------------------------------------------------------------------
__global__ __launch_bounds__(256) void bn_y(const float* __restrict__ ypre,
                                            const float* __restrict__ stats,
                                            const float* __restrict__ lg,
                                            const float* __restrict__ lb,
                                            float* __restrict__ out1) {
    __shared__ float tile[64 * 133];
    __shared__ float pa[128], pc[128];
    int blk = blockIdx.x;
    int b = blk >> 4;
    int s0 = (blk & 15) * 64;
    int t = threadIdx.x;
    if (t < 128) {
        float s1 = 0.f, s2 = 0.f;
        for (int s = 0; s < N_SLOTS; s++) {
            s1 += stats[s * ST_STRIDE + ST_S1_Y + t];
            s2 += stats[s * ST_STRIDE + ST_S2_Y + t];
        }
        const float inv = 1.f / (float)BS;
        float m = s1 * inv;
        float v = s2 * inv - m * m;
        float a = lg[t] * rsqrtf(v + 1e-5f);
        pa[t] = a;
        pc[t] = lb[t] - m * a;
    }
#pragma unroll
    for (int i = 0; i < 32; i++) {
        int idx = i * 256 + t;
        int s = idx >> 7, c = idx & 127;
        tile[s * 133 + c] = ypre[(((size_t)b << 10) + s0 + s) * 128 + c];
    }
    __syncthreads();
#pragma unroll
    for (int i = 0; i < 32; i++) {
        int idx = i * 256 + t;
        int c = idx >> 6, s = idx & 63;
        float v = tile[s * 133 + c];
        out1[((size_t)b * 128 + c) * 1024 + s0 + s] =
            fmaxf(fmaf(v, pa[c], pc[c]), 0.f);
    }
}

// ------------------------------------------------------------------
extern "C" void kernel_launch(void* const* d_in, const int* in_sizes, int n_in,
                              void* d_out, int out_size, void* d_ws, size_t ws_size,
                              hipStream_t stream) {
    const float* xyz    = (const float*)d_in[0];
    const float* points = (const float*)d_in[1];
    const float* c1_w = (const float*)d_in[2];
    const float* c1_b = (const float*)d_in[3];
    const float* g1   = (const float*)d_in[4];
    const float* b1   = (const float*)d_in[5];
    const float* c2_w = (const float*)d_in[6];
    const float* c2_b = (const float*)d_in[7];
    const float* g2   = (const float*)d_in[8];
    const float* b2   = (const float*)d_in[9];
    const float* w0_w = (const float*)d_in[10];
    const float* w0_b = (const float*)d_in[11];
    const float* w0_g = (const float*)d_in[12];
    const float* w0_be= (const float*)d_in[13];
    const float* w1_w = (const float*)d_in[14];
    const float* w1_b = (const float*)d_in[15];
    const float* w1_g = (const float*)d_in[16];
    const float* w1_be= (const float*)d_in[17];
    const float* w2_w = (const float*)d_in[18];
    const float* w2_b = (const float*)d_in[19];
    const float* w2_g = (const float*)d_in[20];
    const float* w2_be= (const float*)d_in[21];
    const float* lin_w= (const float*)d_in[22];
    const float* lin_b= (const float*)d_in[23];
    const float* lg   = (const float*)d_in[24];
    const float* lb   = (const float*)d_in[25];

    float* out0 = (float*)d_out;
    float* out1 = out0 + (size_t)BB * 3 * SS;

    char* wsb = (char*)d_ws;
    int*   nidx    = (int*)(wsb + 0);                         // 1,048,576
    float* offs    = (float*)(wsb + 1048576);                 // 3,145,728
    float* new_xyz = (float*)(wsb + 4194304);                 // 98,304
    float* ypre    = (float*)(wsb + 4292608);                 // 4,194,304
    __hip_bfloat16* ptsT = (__hip_bfloat16*)(wsb + 8486912);  // 4,194,304
    float* w1t     = (float*)(wsb + 12681216);                // 16,384
    float* w2t     = (float*)(wsb + 12697600);                // 32,768 (tier2: packed bf16 hi/lo)
    __hip_bfloat16* linB = (__hip_bfloat16*)(wsb + 12730368); // 524,288
    float* stats   = (float*)(wsb + 13254656);                // 180,224
    float* params  = (float*)(wsb + 13434880);                // 2,816 (floats [448,704) unused)
    int*   progress= (int*)(wsb + 13436672);                  // 64 B inside unused params tail
    float* featsF  = (float*)(wsb + 13437696);                // 67,108,864
    float* f1pre   = featsF;                                  // alias: f1pre dead before feats written
    float* f2pre   = (float*)(wsb + 80546560);                // 134,217,728 (tier-2 only)

    const size_t NEED1 = 13437696ull + 67108864ull;               // 80,546,560
    const size_t NEED2 = 80546560ull + 134217728ull;              // 214,764,288
    const int tier = (ws_size >= NEED2) ? 2 : (ws_size >= NEED1) ? 1 : 0;

    hipMemsetAsync(stats, 0, N_SLOTS * ST_STRIDE * sizeof(float), stream);
    hipMemsetAsync(progress, 0, 64, stream);

    // prep + FPS + streaming kNN; 82KB LDS => 1 block/CU (exclusive FPS CUs)
    prep_fps_knn<<<3640, 256, 0, stream>>>(points, ptsT, c1_w, c2_w, lin_w, w1t, w2t,
                                           linB, xyz, new_xyz, out0,
                                           progress, nidx, offs,
                                           tier == 2 ? 1 : 0);

    pass_a<<<BS, 256, 0, stream>>>(ptsT, nidx, offs, w1t, c1_b, w0_w, w0_b, stats,
                                   f1pre, tier == 2 ? 1 : 0);
    finalize_two<<<2, 128, 0, stream>>>(stats, params,
                                        g1, b1, ST_S1_C1, ST_S2_C1, PA_A_C1, PA_C_C1, 64, 1.f / BSK,
                                        w0_g, w0_be, ST_S1_W0, ST_S2_W0, PA_A_W0, PA_C_W0, 8, 1.f / BSK);

    if (tier == 2) {
        pass_b2<<<BS, 256, 0, stream>>>(f1pre, offs, (const unsigned short*)w2t, c2_b,
                                        w0_w, w0_b, w1_w, w1_b, params, stats, f2pre);
    } else {
        pass_b<<<BS, 256, 0, stream>>>(ptsT, nidx, offs, w1t, c1_b, w2t, c2_b,
                                       w0_w, w0_b, w1_w, w1_b, params, stats);
    }
    finalize_two<<<2, 128, 0, stream>>>(stats, params,
                                        g2, b2, ST_S1_C2, ST_S2_C2, PA_A_C2, PA_C_C2, 128, 1.f / BSK,
                                        w1_g, w1_be, ST_S1_W1, ST_S2_W1, PA_A_W1, PA_C_W1, 8, 1.f / BSK);

    pass_w2<<<BSK / 256, 256, 0, stream>>>(offs, w0_w, w0_b, w1_w, w1_b, w2_w, w2_b,
                                           params, stats);
    finalize_bn<<<1, 128, 0, stream>>>(stats, params, w2_g, w2_be,
                                       ST_S1_W2, ST_S2_W2, PA_A_W2, PA_C_W2, 16, 1.f / BSK);

    if (tier == 2) {
        tail_nl2<<<BS, 256, 0, stream>>>(f2pre, offs, w0_w, w0_b, w1_w, w1_b,
                                         w2_w, w2_b, params, featsF);
        linear_mm16<<<BS / 16, 256, 0, stream>>>(featsF, linB, lin_b, stats, ypre);
    } else {
        fused_tail_nl<<<BS, 256, 0, stream>>>(ptsT, nidx, offs, w1t, c1_b, w2t, c2_b,
                                              w0_w, w0_b, w1_w, w1_b, w2_w, w2_b,
                                              params, featsF);
        linear_mm16<<<BS / 16, 256, 0, stream>>>(featsF, linB, lin_b, stats, ypre);
    }

    bn_y<<<BB * 16, 256, 0, stream>>>(ypre, stats, lg, lb, out1);
}

// Round 13
// 924.221 us; speedup vs baseline: 1.1765x; 1.0720x over previous
//
#include <hip/hip_runtime.h>
#include <hip/hip_bf16.h>

#define BB 8
#define NN 4096
#define DD 64
#define SS 1024
#define KK 32
#define C1 64
#define C2 128

typedef unsigned int uint32;
typedef unsigned long long uint64;

constexpr int BSK = BB * SS * KK;   // 262144
constexpr int BS  = BB * SS;        // 8192

// ---- per-slot stats offsets (slot stride = 704 floats, 64 slots) ----
#define ST_S1_C1 0
#define ST_S2_C1 64
#define ST_S1_C2 128
#define ST_S2_C2 256
#define ST_S1_W0 384
#define ST_S2_W0 392
#define ST_S1_W1 400
#define ST_S2_W1 408
#define ST_S1_W2 416
#define ST_S2_W2 432
#define ST_S1_Y  448
#define ST_S2_Y  576
#define ST_STRIDE 704
#define N_SLOTS 64

#define PA_A_C1 0
#define PA_C_C1 64
#define PA_A_C2 128
#define PA_C_C2 256
#define PA_A_W0 384
#define PA_C_W0 392
#define PA_A_W1 400
#define PA_C_W1 408
#define PA_A_W2 416
#define PA_C_W2 432
// params floats [448, 704) are unused -> progress counters live there

// ------------------------------------------------------------------
// DPP cross-lane helpers (packed-key trick, see prior session notes)
// ------------------------------------------------------------------
#if __has_builtin(__builtin_amdgcn_update_dpp)
#define HAS_DPP 1
template <int CTRL>
__device__ __forceinline__ double dpp_f64(double x) {
    uint64 u = (uint64)__double_as_longlong(x);
    int lo = (int)(uint32)u, hi = (int)(uint32)(u >> 32);
    int lo2 = __builtin_amdgcn_update_dpp(lo, lo, CTRL, 0xf, 0xf, false);
    int hi2 = __builtin_amdgcn_update_dpp(hi, hi, CTRL, 0xf, 0xf, false);
    return __longlong_as_double((long long)(((uint64)(uint32)hi2 << 32) | (uint32)lo2));
}
__device__ __forceinline__ double wave_max_pack(double k) {
    k = fmax(k, dpp_f64<0x111>(k));
    k = fmax(k, dpp_f64<0x112>(k));
    k = fmax(k, dpp_f64<0x114>(k));
    k = fmax(k, dpp_f64<0x118>(k));
    k = fmax(k, dpp_f64<0x142>(k));
    k = fmax(k, dpp_f64<0x143>(k));
    return k;                          // lane 63 holds wave max
}
__device__ __forceinline__ double wave_min_pack(double k) {
    k = fmin(k, dpp_f64<0x111>(k));
    k = fmin(k, dpp_f64<0x112>(k));
    k = fmin(k, dpp_f64<0x114>(k));
    k = fmin(k, dpp_f64<0x118>(k));
    k = fmin(k, dpp_f64<0x142>(k));
    k = fmin(k, dpp_f64<0x143>(k));
    return k;                          // lane 63 holds wave min
}
__device__ __forceinline__ uint64 bcast63_u64(double k) {
#if __has_builtin(__builtin_amdgcn_readlane)
    uint64 u = (uint64)__double_as_longlong(k);
    int lo = __builtin_amdgcn_readlane((int)(uint32)u, 63);
    int hi = __builtin_amdgcn_readlane((int)(uint32)(u >> 32), 63);
    return ((uint64)(uint32)hi << 32) | (uint32)lo;
#else
    return (uint64)__double_as_longlong(__shfl(k, 63));
#endif
}
#define FPS_WRITER_LANE 63
template <int CTRL>
__device__ __forceinline__ float dpp_mov_f32(float x) {
    int r = __builtin_amdgcn_update_dpp(__float_as_int(x), __float_as_int(x),
                                        CTRL, 0xf, 0xf, false);
    return __int_as_float(r);
}
__device__ __forceinline__ float wave_sum_f32(float v) {
    v += dpp_mov_f32<0x111>(v);
    v += dpp_mov_f32<0x112>(v);
    v += dpp_mov_f32<0x114>(v);
    v += dpp_mov_f32<0x118>(v);
    v += dpp_mov_f32<0x142>(v);
    v += dpp_mov_f32<0x143>(v);
    return v;                          // lane 63 holds wave sum
}
#define LIN_WRITER 63
#else
#define HAS_DPP 0
__device__ __forceinline__ double wave_max_pack(double k) {
#pragma unroll
    for (int m = 32; m >= 1; m >>= 1) k = fmax(k, __shfl_xor(k, m));
    return k;
}
__device__ __forceinline__ double wave_min_pack(double k) {
#pragma unroll
    for (int m = 32; m >= 1; m >>= 1) k = fmin(k, __shfl_xor(k, m));
    return k;
}
__device__ __forceinline__ uint64 bcast63_u64(double k) {
    return (uint64)__double_as_longlong(k);
}
#define FPS_WRITER_LANE 0
__device__ __forceinline__ float wave_sum_f32(float v) {
#pragma unroll
    for (int m = 32; m >= 1; m >>= 1) v += __shfl_xor(v, m);
    return v;
}
#define LIN_WRITER 0
#endif

// exact RNE f32 -> bf16 bits
__device__ __forceinline__ uint32 bf16rne(float x) {
    uint32 u = __float_as_uint(x);
    return (u + 0x7fffu + ((u >> 16) & 1u)) >> 16;
}

// MFMA fragment types (guide-blessed)
typedef __attribute__((ext_vector_type(8))) short bf16x8;
typedef __attribute__((ext_vector_type(4))) float f32x4v;

// ------------------------------------------------------------------
// staging: gather 32 neighbors x 64 dims (bf16 -> fp32 LDS)
// ------------------------------------------------------------------
__device__ __forceinline__ void stage_pts(const __hip_bfloat16* __restrict__ ptsT,
                                          const int* __restrict__ nidx,
                                          int q, int b, int t, float* pts) {
    int k = t >> 3, d8 = t & 7;
    int nn = nidx[(size_t)q * KK + k];
    uint4 u = ((const uint4*)ptsT)[((size_t)b * NN + nn) * 8 + d8];
    float4 lo, hi;
    lo.x = __uint_as_float(u.x << 16); lo.y = __uint_as_float(u.x & 0xffff0000u);
    lo.z = __uint_as_float(u.y << 16); lo.w = __uint_as_float(u.y & 0xffff0000u);
    hi.x = __uint_as_float(u.z << 16); hi.y = __uint_as_float(u.z & 0xffff0000u);
    hi.z = __uint_as_float(u.w << 16); hi.w = __uint_as_float(u.w & 0xffff0000u);
    *(float4*)&pts[k * 64 + d8 * 8] = lo;
    *(float4*)&pts[k * 64 + d8 * 8 + 4] = hi;
}

// ------------------------------------------------------------------
// prep_fps_knn (r10 structure, measured 645-653us): blocks [0,8) FPS
// with streaming publish; [8,520) points transpose; [520,1592) weight
// transposes (when pack: w1 AND w2 are written as MFMA B-fragment
// bf16 hi/lo into the w1t/w2t buffers — tier-2 never reads plain
// transposes); [1592,3640) kNN consumers. 82,048 B LDS => 1 block/CU.
// ------------------------------------------------------------------
__global__ __launch_bounds__(256) void prep_fps_knn(const float* __restrict__ points,
                                                    __hip_bfloat16* __restrict__ ptsT,
                                                    const float* __restrict__ c1_w,
                                                    const float* __restrict__ c2_w,
                                                    const float* __restrict__ lin_w,
                                                    float* __restrict__ w1t,
                                                    float* __restrict__ w2t,
                                                    __hip_bfloat16* __restrict__ linB,
                                                    const float* __restrict__ xyz,
                                                    float* __restrict__ new_xyz,
                                                    float* __restrict__ out0,
                                                    int* __restrict__ progress,
                                                    int* __restrict__ nidx,
                                                    float* __restrict__ offs,
                                                    int pack) {
    __shared__ __align__(16) char smu[82048];   // >81,920 B => 1 block/CU
    int t = threadIdx.x;
    int blk = blockIdx.x;
    if (blk < 8) {
        // -------- FPS (exclusive CU) --------
        __builtin_amdgcn_s_setprio(3);
        float4* xyz4 = (float4*)smu;              // [NN] 65536 B
        int* hist = (int*)(smu + 65536);          // [SS] 4096 B
        double* slots = (double*)(smu + 69632);   // [2][4] 64 B
        int b = blk;
        int wv = t >> 6, lane = t & 63;
        const float* base = xyz + (size_t)b * 3 * NN;
        float px[16], py[16], pz[16], dl[16];
        uint32 lidx[16];
#pragma unroll
        for (int i = 0; i < 16; i++) {
            int n = t + 256 * i;
            px[i] = base[n];
            py[i] = base[NN + n];
            pz[i] = base[2 * NN + n];
            float4 v; v.x = px[i]; v.y = py[i]; v.z = pz[i]; v.w = 0.f;
            xyz4[n] = v;
            dl[i] = 1e10f;
            lidx[i] = (uint32)(NN - 1 - n);
        }
        if (t == 0) hist[0] = 0;
        __syncthreads();
        int far = 0;
        for (int step = 1; step < SS; step++) {
            int p = step & 1;
            float4 c = xyz4[far];                 // one b128 broadcast read
            float cx = c.x, cy = c.y, cz = c.z;
            double k0 = 0.0, k1 = 0.0, k2 = 0.0, k3 = 0.0;
#pragma unroll
            for (int i = 0; i < 16; i++) {
                // EXACT arithmetic (must match jax reference bit-for-bit)
                float dx = __fsub_rn(px[i], cx);
                float dy = __fsub_rn(py[i], cy);
                float dz = __fsub_rn(pz[i], cz);
                float d = __fadd_rn(__fadd_rn(__fmul_rn(dx, dx), __fmul_rn(dy, dy)),
                                    __fmul_rn(dz, dz));
                float nd = fminf(dl[i], d);
                dl[i] = nd;
                uint64 kbits = ((uint64)__float_as_uint(nd) << 32) | lidx[i];
                double kk = __longlong_as_double((long long)kbits);
                if ((i & 3) == 0) k0 = fmax(k0, kk);
                else if ((i & 3) == 1) k1 = fmax(k1, kk);
                else if ((i & 3) == 2) k2 = fmax(k2, kk);
                else k3 = fmax(k3, kk);
            }
            double kbest = fmax(fmax(k0, k1), fmax(k2, k3));
            kbest = wave_max_pack(kbest);
            if (lane == FPS_WRITER_LANE) slots[p * 4 + wv] = kbest;
            __syncthreads();
            double s0 = slots[p * 4 + 0], s1 = slots[p * 4 + 1];
            double s2 = slots[p * 4 + 2], s3 = slots[p * 4 + 3];
            double bk = fmax(fmax(s0, s1), fmax(s2, s3));
            uint64 kb = (uint64)__double_as_longlong(bk);
            int bbx = (NN - 1) - (int)(uint32)(kb & 0xffffffffull);
            far = bbx;
            if (t == 0) hist[step] = bbx;
            // streaming publish: every 32 steps, wave-0 lanes 0-31 push
            // entries [step-33, step-1) then lane 0 release-stores progress.
            if ((step & 31) == 1 && step > 32) {
                if (t < 32) {
                    int s2p = step - 33 + t;
                    int idx2 = hist[s2p];
                    float4 v2 = xyz4[idx2];
                    size_t qq = (size_t)(b * SS + s2p) * 3;
                    new_xyz[qq + 0] = v2.x;
                    new_xyz[qq + 1] = v2.y;
                    new_xyz[qq + 2] = v2.z;
                }
                if (t == 0)
                    __hip_atomic_store(&progress[b], step - 1, __ATOMIC_RELEASE,
                                       __HIP_MEMORY_SCOPE_AGENT);
            }
        }
        __syncthreads();
        // epilogue: coalesced output writes
        for (int s = t; s < SS; s += 256) {
            int idx = hist[s];
            float4 v = xyz4[idx];
            size_t q = (size_t)(b * SS + s);
            new_xyz[q * 3 + 0] = v.x;
            new_xyz[q * 3 + 1] = v.y;
            new_xyz[q * 3 + 2] = v.z;
            out0[(size_t)b * 3 * SS + 0 * SS + s] = v.x;
            out0[(size_t)b * 3 * SS + 1 * SS + s] = v.y;
            out0[(size_t)b * 3 * SS + 2 * SS + s] = v.z;
        }
        __threadfence();
        __syncthreads();
        if (t == 0)
            __hip_atomic_store(&progress[b], SS, __ATOMIC_RELEASE,
                               __HIP_MEMORY_SCOPE_AGENT);
        __builtin_amdgcn_s_setprio(0);
    } else if (blk < 520) {
        // -------- points transpose --------
        float (*tile)[65] = (float(*)[65])smu;
        int bb = blk - 8;
        int b = bb >> 6;
        int n0 = (bb & 63) * 64;
        for (int i = t; i < 4096; i += 256) {
            int d = i >> 6, n = i & 63;
            tile[d][n] = points[((size_t)b * DD + d) * NN + n0 + n];
        }
        __syncthreads();
        for (int i = t; i < 4096; i += 256) {
            int n = i >> 6, d = i & 63;
            ptsT[((size_t)b * NN + n0 + n) * DD + d] = __float2bfloat16(tile[d][n]);
        }
    } else if (blk < 1592) {
        // -------- weight transposes + lin_w -> bf16 --------
        int i = (blk - 520) * 256 + t;
        if (i < 4096) {
            if (!pack) {
                int d = i >> 6, c = i & 63;
                w1t[d * 64 + c] = c1_w[c * 64 + d];
            } else {
                // w1 MFMA B-frag bf16 hi/lo into w1t bytes (8192 shorts):
                // j = s*2048 + nf*512 + lg*128 + ln*8 + jj
                int j = i;
                int jj = j & 7, lnn = (j >> 3) & 15, lgg = (j >> 7) & 3;
                int nf = (j >> 9) & 3, s = (j >> 11) & 1;
                int d = s * 32 + lgg * 8 + jj;
                int c = nf * 16 + lnn;
                float v = c1_w[c * 64 + d];
                uint32 hb = bf16rne(v);
                float hif = __uint_as_float(hb << 16);
                uint32 lb2 = bf16rne(v - hif);
                unsigned short* w1p = (unsigned short*)w1t;
                w1p[j] = (unsigned short)hb;
                w1p[4096 + j] = (unsigned short)lb2;
            }
        }
        int j = i - 4096;
        if (j >= 0 && j < 8192) {
            if (!pack) {
                int d = j >> 7, c = j & 127;
                w2t[d * 128 + c] = c2_w[c * 64 + d];
            } else {
                // w2 MFMA B-frag bf16 hi/lo into w2t bytes:
                // j = (((s*8+nf)*4+lg)*16+ln)*8+jj
                int jj = j & 7, lnn = (j >> 3) & 15, lgg = (j >> 7) & 3;
                int nf = (j >> 9) & 7, s = (j >> 12) & 1;
                int d = s * 32 + lgg * 8 + jj;
                int c = nf * 16 + lnn;
                float v = c2_w[c * 64 + d];
                uint32 hb = bf16rne(v);
                float hif = __uint_as_float(hb << 16);
                uint32 lb2 = bf16rne(v - hif);
                unsigned short* w2p = (unsigned short*)w2t;
                w2p[j] = (unsigned short)hb;
                w2p[8192 + j] = (unsigned short)lb2;
            }
        }
        int l = i - 12288;
        if (l >= 0 && l < 262144) linB[l] = __float2bfloat16(lin_w[l]);
    } else {
        // -------- kNN consumer: one wave per query, interleaved map --------
        int cb = blk - 1592;                  // 0..2047
        int wv = t >> 6, lane = t & 63;
        int bq = cb & 7;                      // batch
        int pos = ((cb >> 3) << 2) + wv;      // position within batch
        int q = bq * SS + pos;                // global query
        int needed = pos + 1;
        while (__hip_atomic_load(&progress[bq], __ATOMIC_ACQUIRE,
                                 __HIP_MEMORY_SCOPE_AGENT) < needed)
            __builtin_amdgcn_s_sleep(32);
        const float* base = xyz + (size_t)bq * 3 * NN;
        float sx = new_xyz[(size_t)q * 3 + 0];
        float sy = new_xyz[(size_t)q * 3 + 1];
        float sz = new_xyz[(size_t)q * 3 + 2];
        float s2 = __fadd_rn(__fadd_rn(__fmul_rn(sx, sx), __fmul_rn(sy, sy)), __fmul_rn(sz, sz));
        float dl[64];
#pragma unroll
        for (int i = 0; i < 64; i++) {
            int n = i * 64 + lane;
            float x = base[n], y = base[NN + n], z = base[2 * NN + n];
            float d2 = __fadd_rn(__fadd_rn(__fmul_rn(x, x), __fmul_rn(y, y)), __fmul_rn(z, z));
            float dot = __fadd_rn(__fadd_rn(__fmul_rn(sx, x), __fmul_rn(sy, y)), __fmul_rn(sz, z));
            float v = __fmul_rn(-2.0f, dot);
            v = __fadd_rn(v, s2);
            v = __fadd_rn(v, d2);
            dl[i] = v;
        }
        const float MASKF = __uint_as_float(0x7F7FFFFFu);   // FLT_MAX
        unsigned long long excl = 0ull;
        for (int k = 0; k < KK; k++) {
            float best = MASKF;
            int bslot = 0;
#pragma unroll
            for (int i = 0; i < 64; i++) {
                bool ok = ((excl >> i) & 1ull) == 0ull;
                float v = ok ? dl[i] : MASKF;
                if (v < best) { best = v; bslot = i; }
            }
            uint64 kbits = ((uint64)__float_as_uint(best) << 32) |
                           (uint32)(bslot * 64 + lane);
            double kb = wave_min_pack(__longlong_as_double((long long)kbits));
            uint64 r = bcast63_u64(kb);
            int bi = (int)(uint32)(r & 0xffffffffull);
            if ((bi & 63) == lane) excl |= (1ull << (bi >> 6));
            if (lane == 0) {
                nidx[(size_t)q * KK + k] = bi;
                size_t oo = ((size_t)q * KK + k) * 3;
                offs[oo + 0] = __fsub_rn(base[bi], sx);
                offs[oo + 1] = __fsub_rn(base[NN + bi], sy);
                offs[oo + 2] = __fsub_rn(base[2 * NN + bi], sz);
            }
        }
    }
}

// ------------------------------------------------------------------
// pass A (tier<2 fallback): scalar conv1 stats + w0 stats
// ------------------------------------------------------------------
__global__ __launch_bounds__(256) void pass_a(const __hip_bfloat16* __restrict__ ptsT,
                                              const int* __restrict__ nidx,
                                              const float* __restrict__ offs,
                                              const float* __restrict__ w1t,
                                              const float* __restrict__ c1_b,
                                              const float* __restrict__ w0_w,
                                              const float* __restrict__ w0_b,
                                              float* __restrict__ stats) {
    __shared__ __align__(16) float pts[2048];
    __shared__ float red1[256], red2[256];
    int blk = blockIdx.x, t = threadIdx.x;
    int b = blk >> 10;
    int slot = blk & (N_SLOTS - 1);
    stage_pts(ptsT, nidx, blk, b, t, pts);
    __syncthreads();
    int c = t & 63, kg = t >> 6;
    float bias = c1_b[c];
    float acc[8];
#pragma unroll
    for (int j = 0; j < 8; j++) acc[j] = bias;
    for (int d4 = 0; d4 < 16; d4++) {
        float w0 = w1t[(4 * d4 + 0) * 64 + c];
        float w1v = w1t[(4 * d4 + 1) * 64 + c];
        float w2v = w1t[(4 * d4 + 2) * 64 + c];
        float w3 = w1t[(4 * d4 + 3) * 64 + c];
#pragma unroll
        for (int j = 0; j < 8; j++) {
            const float4 p = *(const float4*)&pts[(kg + 4 * j) * 64 + 4 * d4];
            acc[j] = fmaf(p.x, w0, acc[j]);
            acc[j] = fmaf(p.y, w1v, acc[j]);
            acc[j] = fmaf(p.z, w2v, acc[j]);
            acc[j] = fmaf(p.w, w3, acc[j]);
        }
    }
    float s1 = 0.f, s2 = 0.f;
#pragma unroll
    for (int j = 0; j < 8; j++) { s1 += acc[j]; s2 += acc[j] * acc[j]; }
    red1[t] = s1;
    red2[t] = s2;
    __syncthreads();
    if (t < 64) {
        atomicAdd(&stats[slot * ST_STRIDE + ST_S1_C1 + t],
                  red1[t] + red1[t + 64] + red1[t + 128] + red1[t + 192]);
        atomicAdd(&stats[slot * ST_STRIDE + ST_S2_C1 + t],
                  red2[t] + red2[t + 64] + red2[t + 128] + red2[t + 192]);
    }
    int k0 = t >> 3, c0 = t & 7;
    size_t oo = ((size_t)blk * KK + k0) * 3;
    float h = w0_b[c0];
    h = fmaf(offs[oo + 0], w0_w[c0 * 3 + 0], h);
    h = fmaf(offs[oo + 1], w0_w[c0 * 3 + 1], h);
    h = fmaf(offs[oo + 2], w0_w[c0 * 3 + 2], h);
    __syncthreads();
    red1[t] = h;
    red2[t] = h * h;
    __syncthreads();
    if (t < 8) {
        float a = 0.f, q = 0.f;
        for (int j = t; j < 256; j += 8) { a += red1[j]; q += red2[j]; }
        atomicAdd(&stats[slot * ST_STRIDE + ST_S1_W0 + t], a);
        atomicAdd(&stats[slot * ST_STRIDE + ST_S2_W0 + t], q);
    }
}

// ------------------------------------------------------------------
// pass A2 (tier-2, MFMA): gather bf16 direct to LDS (exact A operand),
// conv1 via mfma_f32_16x16x32_bf16 with 2-product B hi/lo split
// (A exact bf16; A·Bh + A·Bl) against pre-packed w1; f1pre + c1 stats
// from fragments; w0 stats scalar (unchanged).
// ------------------------------------------------------------------
__global__ __launch_bounds__(256) void pass_a2(const __hip_bfloat16* __restrict__ ptsT,
                                               const int* __restrict__ nidx,
                                               const float* __restrict__ offs,
                                               const unsigned short* __restrict__ w1pack,
                                               const float* __restrict__ c1_b,
                                               const float* __restrict__ w0_w,
                                               const float* __restrict__ w0_b,
                                               float* __restrict__ stats,
                                               float* __restrict__ f1pre) {
    __shared__ __align__(16) unsigned short ptsB[32 * 72];   // 4608 B
    __shared__ float red1[256], red2[256];
    int blk = blockIdx.x, t = threadIdx.x;
    int b = blk >> 10;
    int slot = blk & (N_SLOTS - 1);
    // gather directly as bf16 (no f32 unpack)
    {
        int k = t >> 3, d8 = t & 7;
        int nn = nidx[(size_t)blk * KK + k];
        uint4 u = ((const uint4*)ptsT)[((size_t)b * NN + nn) * 8 + d8];
        *(uint4*)&ptsB[k * 72 + d8 * 8] = u;
    }
    __syncthreads();
    int lane = t & 63, w = t >> 6;
    int lg = lane >> 4, ln = lane & 15;
    f32x4v acc0 = {0.f, 0.f, 0.f, 0.f};   // rows 0..15  (mf0)
    f32x4v acc1 = {0.f, 0.f, 0.f, 0.f};   // rows 16..31 (mf1)
#pragma unroll
    for (int s = 0; s < 2; s++) {
        int ao = s * 32 + lg * 8;
        bf16x8 a0 = *(const bf16x8*)&ptsB[ln * 72 + ao];
        bf16x8 a1 = *(const bf16x8*)&ptsB[(16 + ln) * 72 + ao];
        int boff = (((s * 4 + w) * 4 + lg) * 16 + ln) * 8;
        bf16x8 bh = *(const bf16x8*)&w1pack[boff];
        bf16x8 bl = *(const bf16x8*)&w1pack[4096 + boff];
        acc0 = __builtin_amdgcn_mfma_f32_16x16x32_bf16(a0, bh, acc0, 0, 0, 0);
        acc0 = __builtin_amdgcn_mfma_f32_16x16x32_bf16(a0, bl, acc0, 0, 0, 0);
        acc1 = __builtin_amdgcn_mfma_f32_16x16x32_bf16(a1, bh, acc1, 0, 0, 0);
        acc1 = __builtin_amdgcn_mfma_f32_16x16x32_bf16(a1, bl, acc1, 0, 0, 0);
    }
    // epilogue: +bias, write f1pre [k*64+c], c1 stats via shfl reduce
    {
        int c = w * 16 + ln;
        float bias = c1_b[c];
        float p1 = 0.f, p2 = 0.f;
#pragma unroll
        for (int r = 0; r < 4; r++) {
            int m0 = lg * 4 + r;          // C/D row = (lane>>4)*4 + reg
            int m1 = 16 + lg * 4 + r;
            float v0 = acc0[r] + bias;
            float v1 = acc1[r] + bias;
            f1pre[(size_t)blk * 2048 + m0 * 64 + c] = v0;
            f1pre[(size_t)blk * 2048 + m1 * 64 + c] = v1;
            p1 += v0 + v1; p2 += v0 * v0 + v1 * v1;
        }
        p1 += __shfl_xor(p1, 16); p1 += __shfl_xor(p1, 32);
        p2 += __shfl_xor(p2, 16); p2 += __shfl_xor(p2, 32);
        if (lg == 0) {
            atomicAdd(&stats[slot * ST_STRIDE + ST_S1_C1 + c], p1);
            atomicAdd(&stats[slot * ST_STRIDE + ST_S2_C1 + c], p2);
        }
    }
    // w0 stats (scalar, unchanged)
    {
        int k0 = t >> 3, c0 = t & 7;
        size_t oo = ((size_t)blk * KK + k0) * 3;
        float h = w0_b[c0];
        h = fmaf(offs[oo + 0], w0_w[c0 * 3 + 0], h);
        h = fmaf(offs[oo + 1], w0_w[c0 * 3 + 1], h);
        h = fmaf(offs[oo + 2], w0_w[c0 * 3 + 2], h);
        red1[t] = h;
        red2[t] = h * h;
        __syncthreads();
        if (t < 8) {
            float a = 0.f, q = 0.f;
            for (int j = t; j < 256; j += 8) { a += red1[j]; q += red2[j]; }
            atomicAdd(&stats[slot * ST_STRIDE + ST_S1_W0 + t], a);
            atomicAdd(&stats[slot * ST_STRIDE + ST_S2_W0 + t], q);
        }
    }
}

// ------------------------------------------------------------------
// finalize BN(s) from slotted stats
// ------------------------------------------------------------------
__device__ __forceinline__ void fin_one(const float* stats, float* params,
                                        const float* g, const float* be,
                                        int s1o, int s2o, int ao, int co,
                                        int nch, float inv, int t) {
    if (t < nch) {
        float s1 = 0.f, s2 = 0.f;
        for (int s = 0; s < N_SLOTS; s++) {
            s1 += stats[s * ST_STRIDE + s1o + t];
            s2 += stats[s * ST_STRIDE + s2o + t];
        }
        float m = s1 * inv;
        float v = s2 * inv - m * m;
        float a = g[t] * rsqrtf(v + 1e-5f);
        params[ao + t] = a;
        params[co + t] = be[t] - m * a;
    }
}

__global__ void finalize_bn(const float* __restrict__ stats, float* __restrict__ params,
                            const float* __restrict__ g, const float* __restrict__ be,
                            int s1o, int s2o, int ao, int co, int nch, float inv) {
    fin_one(stats, params, g, be, s1o, s2o, ao, co, nch, inv, threadIdx.x);
}

__global__ void finalize_two(const float* __restrict__ stats, float* __restrict__ params,
                             const float* __restrict__ gA, const float* __restrict__ beA,
                             int s1A, int s2A, int aA, int cA, int nA, float invA,
                             const float* __restrict__ gB, const float* __restrict__ beB,
                             int s1B, int s2B, int aB, int cB, int nB, float invB) {
    if (blockIdx.x == 0)
        fin_one(stats, params, gA, beA, s1A, s2A, aA, cA, nA, invA, threadIdx.x);
    else
        fin_one(stats, params, gB, beB, s1B, s2B, aB, cB, nB, invB, threadIdx.x);
}

// ------------------------------------------------------------------
// pass B (tier-1 fallback): conv1 recompute + bn1relu -> f1; conv2
// stats; w1 stats (uses PLAIN w1t/w2t — only valid when !pack)
// ------------------------------------------------------------------
__global__ __launch_bounds__(256) void pass_b(const __hip_bfloat16* __restrict__ ptsT,
                                              const int* __restrict__ nidx,
                                              const float* __restrict__ offs,
                                              const float* __restrict__ w1t,
                                              const float* __restrict__ c1_b,
                                              const float* __restrict__ w2t,
                                              const float* __restrict__ c2_b,
                                              const float* __restrict__ w0_w,
                                              const float* __restrict__ w0_b,
                                              const float* __restrict__ w1_w,
                                              const float* __restrict__ w1_b,
                                              const float* __restrict__ params,
                                              float* __restrict__ stats) {
    __shared__ __align__(16) float pts[2048];
    __shared__ __align__(16) float f1[2048];
    __shared__ float red1[256], red2[256];
    int blk = blockIdx.x, t = threadIdx.x;
    int b = blk >> 10;
    int slot = blk & (N_SLOTS - 1);
    stage_pts(ptsT, nidx, blk, b, t, pts);
    __syncthreads();
    {
        int c = t & 63, kg = t >> 6;
        float a1 = params[PA_A_C1 + c], cc1 = params[PA_C_C1 + c], bias = c1_b[c];
        float acc[8];
#pragma unroll
        for (int j = 0; j < 8; j++) acc[j] = bias;
        for (int d4 = 0; d4 < 16; d4++) {
            float w0 = w1t[(4 * d4 + 0) * 64 + c];
            float w1v = w1t[(4 * d4 + 1) * 64 + c];
            float w2v = w1t[(4 * d4 + 2) * 64 + c];
            float w3 = w1t[(4 * d4 + 3) * 64 + c];
#pragma unroll
            for (int j = 0; j < 8; j++) {
                const float4 p = *(const float4*)&pts[(kg + 4 * j) * 64 + 4 * d4];
                acc[j] = fmaf(p.x, w0, acc[j]);
                acc[j] = fmaf(p.y, w1v, acc[j]);
                acc[j] = fmaf(p.z, w2v, acc[j]);
                acc[j] = fmaf(p.w, w3, acc[j]);
            }
        }
#pragma unroll
        for (int j = 0; j < 8; j++)
            f1[(kg + 4 * j) * 64 + c] = fmaxf(fmaf(acc[j], a1, cc1), 0.f);
    }
    __syncthreads();
    {
        int c = t & 127, kg = t >> 7;
        float bias = c2_b[c];
        float acc[16];
#pragma unroll
        for (int j = 0; j < 16; j++) acc[j] = bias;
        for (int d4 = 0; d4 < 16; d4++) {
            float w0 = w2t[(4 * d4 + 0) * 128 + c];
            float w1v = w2t[(4 * d4 + 1) * 128 + c];
            float w2v = w2t[(4 * d4 + 2) * 128 + c];
            float w3 = w2t[(4 * d4 + 3) * 128 + c];
#pragma unroll
            for (int j = 0; j < 16; j++) {
                const float4 p = *(const float4*)&f1[(kg + 2 * j) * 64 + 4 * d4];
                acc[j] = fmaf(p.x, w0, acc[j]);
                acc[j] = fmaf(p.y, w1v, acc[j]);
                acc[j] = fmaf(p.z, w2v, acc[j]);
                acc[j] = fmaf(p.w, w3, acc[j]);
            }
        }
        float s1 = 0.f, s2 = 0.f;
#pragma unroll
        for (int j = 0; j < 16; j++) { s1 += acc[j]; s2 += acc[j] * acc[j]; }
        red1[t] = s1;
        red2[t] = s2;
    }
    __syncthreads();
    if (t < 128) {
        atomicAdd(&stats[slot * ST_STRIDE + ST_S1_C2 + t], red1[t] + red1[t + 128]);
        atomicAdd(&stats[slot * ST_STRIDE + ST_S2_C2 + t], red2[t] + red2[t + 128]);
    }
    {
        int k0 = t >> 3, c0 = t & 7;
        size_t oo = ((size_t)blk * KK + k0) * 3;
        float o0 = offs[oo], o1 = offs[oo + 1], o2 = offs[oo + 2];
        float h0[8];
#pragma unroll
        for (int j = 0; j < 8; j++) {
            float hh = w0_b[j];
            hh = fmaf(o0, w0_w[j * 3 + 0], hh);
            hh = fmaf(o1, w0_w[j * 3 + 1], hh);
            hh = fmaf(o2, w0_w[j * 3 + 2], hh);
            h0[j] = fmaxf(fmaf(hh, params[PA_A_W0 + j], params[PA_C_W0 + j]), 0.f);
        }
        float h = w1_b[c0];
#pragma unroll
        for (int j = 0; j < 8; j++) h = fmaf(h0[j], w1_w[c0 * 8 + j], h);
        __syncthreads();
        red1[t] = h;
        red2[t] = h * h;
        __syncthreads();
        if (t < 8) {
            float a = 0.f, q = 0.f;
            for (int j = t; j < 256; j += 8) { a += red1[j]; q += red2[j]; }
            atomicAdd(&stats[slot * ST_STRIDE + ST_S1_W1 + t], a);
            atomicAdd(&stats[slot * ST_STRIDE + ST_S2_W1 + t], q);
        }
    }
}

// ------------------------------------------------------------------
// pass B2 (tier-2, MFMA): read f1pre, bn1relu -> bf16 hi/lo LDS;
// conv2 via mfma with 3-product hi/lo split against pre-packed w2;
// f2pre + c2 stats from fragments; w1 stats unchanged.
// ------------------------------------------------------------------
__global__ __launch_bounds__(256) void pass_b2(const float* __restrict__ f1pre,
                                               const float* __restrict__ offs,
                                               const unsigned short* __restrict__ w2pack,
                                               const float* __restrict__ c2_b,
                                               const float* __restrict__ w0_w,
                                               const float* __restrict__ w0_b,
                                               const float* __restrict__ w1_w,
                                               const float* __restrict__ w1_b,
                                               const float* __restrict__ params,
                                               float* __restrict__ stats,
                                               float* __restrict__ f2pre) {
    __shared__ __align__(16) unsigned short f1h[32 * 72];
    __shared__ __align__(16) unsigned short f1l[32 * 72];
    __shared__ float red1[256], red2[256];
    int blk = blockIdx.x, t = threadIdx.x;
    int slot = blk & (N_SLOTS - 1);
    // bn1relu + hi/lo bf16 split into padded LDS tiles
    {
        int c = t & 63;
        float a1 = params[PA_A_C1 + c], cc1 = params[PA_C_C1 + c];
#pragma unroll
        for (int i = 0; i < 8; i++) {
            int e = i * 256 + t;
            float v = f1pre[(size_t)blk * 2048 + e];
            float f = fmaxf(fmaf(v, a1, cc1), 0.f);
            int k = e >> 6, d = e & 63;
            uint32 hb = bf16rne(f);
            f1h[k * 72 + d] = (unsigned short)hb;
            f1l[k * 72 + d] = (unsigned short)bf16rne(f - __uint_as_float(hb << 16));
        }
    }
    __syncthreads();
    int lane = t & 63, w = t >> 6;
    int lg = lane >> 4, ln = lane & 15;
    f32x4v acc00 = {0.f, 0.f, 0.f, 0.f};   // mf0, nfi0
    f32x4v acc01 = {0.f, 0.f, 0.f, 0.f};   // mf0, nfi1
    f32x4v acc10 = {0.f, 0.f, 0.f, 0.f};   // mf1, nfi0
    f32x4v acc11 = {0.f, 0.f, 0.f, 0.f};   // mf1, nfi1
#pragma unroll
    for (int s = 0; s < 2; s++) {
        int ao = s * 32 + lg * 8;
        bf16x8 ah0 = *(const bf16x8*)&f1h[(ln) * 72 + ao];
        bf16x8 ah1 = *(const bf16x8*)&f1h[(16 + ln) * 72 + ao];
        bf16x8 al0 = *(const bf16x8*)&f1l[(ln) * 72 + ao];
        bf16x8 al1 = *(const bf16x8*)&f1l[(16 + ln) * 72 + ao];
        int nf0 = w * 2, nf1 = w * 2 + 1;
        int b0off = (((s * 8 + nf0) * 4 + lg) * 16 + ln) * 8;
        int b1off = (((s * 8 + nf1) * 4 + lg) * 16 + ln) * 8;
        bf16x8 bh0 = *(const bf16x8*)&w2pack[b0off];
        bf16x8 bl0 = *(const bf16x8*)&w2pack[8192 + b0off];
        bf16x8 bh1 = *(const bf16x8*)&w2pack[b1off];
        bf16x8 bl1 = *(const bf16x8*)&w2pack[8192 + b1off];
        acc00 = __builtin_amdgcn_mfma_f32_16x16x32_bf16(ah0, bh0, acc00, 0, 0, 0);
        acc00 = __builtin_amdgcn_mfma_f32_16x16x32_bf16(al0, bh0, acc00, 0, 0, 0);
        acc00 = __builtin_amdgcn_mfma_f32_16x16x32_bf16(ah0, bl0, acc00, 0, 0, 0);
        acc01 = __builtin_amdgcn_mfma_f32_16x16x32_bf16(ah0, bh1, acc01, 0, 0, 0);
        acc01 = __builtin_amdgcn_mfma_f32_16x16x32_bf16(al0, bh1, acc01, 0, 0, 0);
        acc01 = __builtin_amdgcn_mfma_f32_16x16x32_bf16(ah0, bl1, acc01, 0, 0, 0);
        acc10 = __builtin_amdgcn_mfma_f32_16x16x32_bf16(ah1, bh0, acc10, 0, 0, 0);
        acc10 = __builtin_amdgcn_mfma_f32_16x16x32_bf16(al1, bh0, acc10, 0, 0, 0);
        acc10 = __builtin_amdgcn_mfma_f32_16x16x32_bf16(ah1, bl0, acc10, 0, 0, 0);
        acc11 = __builtin_amdgcn_mfma_f32_16x16x32_bf16(ah1, bh1, acc11, 0, 0, 0);
        acc11 = __builtin_amdgcn_mfma_f32_16x16x32_bf16(al1, bh1, acc11, 0, 0, 0);
        acc11 = __builtin_amdgcn_mfma_f32_16x16x32_bf16(ah1, bl1, acc11, 0, 0, 0);
    }
    // epilogue: +bias, write f2pre [k*128+c], c2 stats via shfl reduce
    {
        int c0 = w * 32 + ln;
        int c1c = w * 32 + 16 + ln;
        float b0 = c2_b[c0], b1 = c2_b[c1c];
        float p10 = 0.f, p20 = 0.f, p11 = 0.f, p21 = 0.f;
#pragma unroll
        for (int r = 0; r < 4; r++) {
            int k0 = lg * 4 + r;          // C/D row = (lane>>4)*4 + reg
            int k1 = 16 + lg * 4 + r;
            float v00 = acc00[r] + b0;
            float v01 = acc01[r] + b1;
            float v10 = acc10[r] + b0;
            float v11 = acc11[r] + b1;
            f2pre[(size_t)blk * 4096 + k0 * 128 + c0]  = v00;
            f2pre[(size_t)blk * 4096 + k0 * 128 + c1c] = v01;
            f2pre[(size_t)blk * 4096 + k1 * 128 + c0]  = v10;
            f2pre[(size_t)blk * 4096 + k1 * 128 + c1c] = v11;
            p10 += v00 + v10; p20 += v00 * v00 + v10 * v10;
            p11 += v01 + v11; p21 += v01 * v01 + v11 * v11;
        }
        p10 += __shfl_xor(p10, 16); p10 += __shfl_xor(p10, 32);
        p20 += __shfl_xor(p20, 16); p20 += __shfl_xor(p20, 32);
        p11 += __shfl_xor(p11, 16); p11 += __shfl_xor(p11, 32);
        p21 += __shfl_xor(p21, 16); p21 += __shfl_xor(p21, 32);
        if (lg == 0) {
            atomicAdd(&stats[slot * ST_STRIDE + ST_S1_C2 + c0], p10);
            atomicAdd(&stats[slot * ST_STRIDE + ST_S2_C2 + c0], p20);
            atomicAdd(&stats[slot * ST_STRIDE + ST_S1_C2 + c1c], p11);
            atomicAdd(&stats[slot * ST_STRIDE + ST_S2_C2 + c1c], p21);
        }
    }
    // w1 stats (unchanged)
    {
        int k0 = t >> 3, c0 = t & 7;
        size_t oo = ((size_t)blk * KK + k0) * 3;
        float o0 = offs[oo], o1 = offs[oo + 1], o2 = offs[oo + 2];
        float h0[8];
#pragma unroll
        for (int j = 0; j < 8; j++) {
            float hh = w0_b[j];
            hh = fmaf(o0, w0_w[j * 3 + 0], hh);
            hh = fmaf(o1, w0_w[j * 3 + 1], hh);
            hh = fmaf(o2, w0_w[j * 3 + 2], hh);
            h0[j] = fmaxf(fmaf(hh, params[PA_A_W0 + j], params[PA_C_W0 + j]), 0.f);
        }
        float h = w1_b[c0];
#pragma unroll
        for (int j = 0; j < 8; j++) h = fmaf(h0[j], w1_w[c0 * 8 + j], h);
        red1[t] = h;
        red2[t] = h * h;
        __syncthreads();
        if (t < 8) {
            float a = 0.f, q = 0.f;
            for (int j = t; j < 256; j += 8) { a += red1[j]; q += red2[j]; }
            atomicAdd(&stats[slot * ST_STRIDE + ST_S1_W1 + t], a);
            atomicAdd(&stats[slot * ST_STRIDE + ST_S2_W1 + t], q);
        }
    }
}

// ------------------------------------------------------------------
// w2 stats (unchanged)
// ------------------------------------------------------------------
__global__ __launch_bounds__(256) void pass_w2(const float* __restrict__ offs,
                                               const float* __restrict__ w0_w,
                                               const float* __restrict__ w0_b,
                                               const float* __restrict__ w1_w,
                                               const float* __restrict__ w1_b,
                                               const float* __restrict__ w2_w,
                                               const float* __restrict__ w2_b,
                                               const float* __restrict__ params,
                                               float* __restrict__ stats) {
    int i = blockIdx.x * 256 + threadIdx.x;
    int slot = blockIdx.x & (N_SLOTS - 1);
    size_t oo = (size_t)i * 3;
    float o0 = offs[oo], o1 = offs[oo + 1], o2 = offs[oo + 2];
    float h0[8], h1[8];
#pragma unroll
    for (int j = 0; j < 8; j++) {
        float hh = w0_b[j];
        hh = fmaf(o0, w0_w[j * 3 + 0], hh);
        hh = fmaf(o1, w0_w[j * 3 + 1], hh);
        hh = fmaf(o2, w0_w[j * 3 + 2], hh);
        h0[j] = fmaxf(fmaf(hh, params[PA_A_W0 + j], params[PA_C_W0 + j]), 0.f);
    }
#pragma unroll
    for (int j = 0; j < 8; j++) {
        float hh = w1_b[j];
#pragma unroll
        for (int q = 0; q < 8; q++) hh = fmaf(h0[q], w1_w[j * 8 + q], hh);
        h1[j] = fmaxf(fmaf(hh, params[PA_A_W1 + j], params[PA_C_W1 + j]), 0.f);
    }
#pragma unroll
    for (int c = 0; c < 16; c++) {
        float h = w2_b[c];
#pragma unroll
        for (int q = 0; q < 8; q++) h = fmaf(h1[q], w2_w[c * 8 + q], h);
        float v = wave_sum_f32(h);
        float s = wave_sum_f32(h * h);
        if ((threadIdx.x & 63) == LIN_WRITER) {
            atomicAdd(&stats[slot * ST_STRIDE + ST_S1_W2 + c], v);
            atomicAdd(&stats[slot * ST_STRIDE + ST_S2_W2 + c], s);
        }
    }
}

// ------------------------------------------------------------------
// weightnet device helper (shared by tails)
// ------------------------------------------------------------------
__device__ __forceinline__ void weightnet_to_lds(const float* __restrict__ offs,
                                                 const float* __restrict__ w0_w,
                                                 const float* __restrict__ w0_b,
                                                 const float* __restrict__ w1_w,
                                                 const float* __restrict__ w1_b,
                                                 const float* __restrict__ w2_w,
                                                 const float* __restrict__ w2_b,
                                                 const float* __restrict__ params,
                                                 int blk, int t, float* wg) {
    for (int idx = t; idx < KK * 16; idx += 256) {
        int k = idx >> 4, cw = idx & 15;
        size_t oo = ((size_t)blk * KK + k) * 3;
        float o0 = offs[oo], o1 = offs[oo + 1], o2 = offs[oo + 2];
        float h0[8], h1[8];
#pragma unroll
        for (int j = 0; j < 8; j++) {
            float hh = w0_b[j];
            hh = fmaf(o0, w0_w[j * 3 + 0], hh);
            hh = fmaf(o1, w0_w[j * 3 + 1], hh);
            hh = fmaf(o2, w0_w[j * 3 + 2], hh);
            h0[j] = fmaxf(fmaf(hh, params[PA_A_W0 + j], params[PA_C_W0 + j]), 0.f);
        }
#pragma unroll
        for (int j = 0; j < 8; j++) {
            float hh = w1_b[j];
#pragma unroll
            for (int q = 0; q < 8; q++) hh = fmaf(h0[q], w1_w[j * 8 + q], hh);
            h1[j] = fmaxf(fmaf(hh, params[PA_A_W1 + j], params[PA_C_W1 + j]), 0.f);
        }
        float h = w2_b[cw];
#pragma unroll
        for (int q = 0; q < 8; q++) h = fmaf(h1[q], w2_w[cw * 8 + q], h);
        wg[idx] = fmaxf(fmaf(h, params[PA_A_W2 + cw], params[PA_C_W2 + cw]), 0.f);
    }
}

// ------------------------------------------------------------------
// tail_nl2 (tier-2): read f2pre + bn2relu -> LDS; weightnet; einsum;
// feats -> global.
// ------------------------------------------------------------------
__global__ __launch_bounds__(256) void tail_nl2(const float* __restrict__ f2pre,
                                                const float* __restrict__ offs,
                                                const float* __restrict__ w0_w,
                                                const float* __restrict__ w0_b,
                                                const float* __restrict__ w1_w,
                                                const float* __restrict__ w1_b,
                                                const float* __restrict__ w2_w,
                                                const float* __restrict__ w2_b,
                                                const float* __restrict__ params,
                                                float* __restrict__ featsF) {
    __shared__ __align__(16) float sm[6656];
    float* f2    = sm;            // [4096]
    float* wg    = sm + 4096;     // [512]
    float* feats = sm + 4608;     // [2048]
    int blk = blockIdx.x, t = threadIdx.x;
    weightnet_to_lds(offs, w0_w, w0_b, w1_w, w1_b, w2_w, w2_b, params, blk, t, wg);
    {
        int c = t & 127;
        float a2 = params[PA_A_C2 + c], cc2 = params[PA_C_C2 + c];
#pragma unroll
        for (int i = 0; i < 16; i++) {
            float v = f2pre[(size_t)blk * 4096 + i * 256 + t];
            f2[i * 256 + t] = fmaxf(fmaf(v, a2, cc2), 0.f);
        }
    }
    __syncthreads();
    {
        int cc = t & 127, wh = t >> 7;
        float acc[8];
#pragma unroll
        for (int i = 0; i < 8; i++) acc[i] = 0.f;
        for (int k = 0; k < KK; k++) {
            float fv = f2[k * 128 + cc];
            const float4 wa = *(const float4*)&wg[k * 16 + 8 * wh];
            const float4 wb = *(const float4*)&wg[k * 16 + 8 * wh + 4];
            acc[0] = fmaf(fv, wa.x, acc[0]);
            acc[1] = fmaf(fv, wa.y, acc[1]);
            acc[2] = fmaf(fv, wa.z, acc[2]);
            acc[3] = fmaf(fv, wa.w, acc[3]);
            acc[4] = fmaf(fv, wb.x, acc[4]);
            acc[5] = fmaf(fv, wb.y, acc[5]);
            acc[6] = fmaf(fv, wb.z, acc[6]);
            acc[7] = fmaf(fv, wb.w, acc[7]);
        }
        *(float4*)&feats[cc * 16 + 8 * wh]     = *(float4*)&acc[0];
        *(float4*)&feats[cc * 16 + 8 * wh + 4] = *(float4*)&acc[4];
    }
    __syncthreads();
#pragma unroll
    for (int i = 0; i < 8; i++)
        featsF[(size_t)blk * 2048 + i * 256 + t] = feats[i * 256 + t];
}

// ------------------------------------------------------------------
// fused_tail_nl (tier-1): full recompute tail (plain w1t/w2t)
// ------------------------------------------------------------------
__global__ __launch_bounds__(256) void fused_tail_nl(
        const __hip_bfloat16* __restrict__ ptsT, const int* __restrict__ nidx,
        const float* __restrict__ offs,
        const float* __restrict__ w1t, const float* __restrict__ c1_b,
        const float* __restrict__ w2t, const float* __restrict__ c2_b,
        const float* __restrict__ w0_w, const float* __restrict__ w0_b,
        const float* __restrict__ w1_w, const float* __restrict__ w1_b,
        const float* __restrict__ w2_w, const float* __restrict__ w2_b,
        const float* __restrict__ params, float* __restrict__ featsF) {
    __shared__ __align__(16) float sm[8704];
    float* pts   = sm;
    float* f1    = sm + 2048;
    float* f2    = sm + 4096;
    float* wg    = sm + 8192;
    int blk = blockIdx.x, t = threadIdx.x;
    int b = blk >> 10;
    stage_pts(ptsT, nidx, blk, b, t, pts);
    weightnet_to_lds(offs, w0_w, w0_b, w1_w, w1_b, w2_w, w2_b, params, blk, t, wg);
    __syncthreads();
    {
        int c = t & 63, kg = t >> 6;
        float a1 = params[PA_A_C1 + c], cc1 = params[PA_C_C1 + c], bias = c1_b[c];
        float acc[8];
#pragma unroll
        for (int j = 0; j < 8; j++) acc[j] = bias;
        for (int d4 = 0; d4 < 16; d4++) {
            float w0 = w1t[(4 * d4 + 0) * 64 + c];
            float w1v = w1t[(4 * d4 + 1) * 64 + c];
            float w2v = w1t[(4 * d4 + 2) * 64 + c];
            float w3 = w1t[(4 * d4 + 3) * 64 + c];
#pragma unroll
            for (int j = 0; j < 8; j++) {
                const float4 p = *(const float4*)&pts[(kg + 4 * j) * 64 + 4 * d4];
                acc[j] = fmaf(p.x, w0, acc[j]);
                acc[j] = fmaf(p.y, w1v, acc[j]);
                acc[j] = fmaf(p.z, w2v, acc[j]);
                acc[j] = fmaf(p.w, w3, acc[j]);
            }
        }
#pragma unroll
        for (int j = 0; j < 8; j++)
            f1[(kg + 4 * j) * 64 + c] = fmaxf(fmaf(acc[j], a1, cc1), 0.f);
    }
    __syncthreads();
    {
        int c = t & 127, kg = t >> 7;
        float a2 = params[PA_A_C2 + c], cc2 = params[PA_C_C2 + c], bias = c2_b[c];
        float acc[16];
#pragma unroll
        for (int j = 0; j < 16; j++) acc[j] = bias;
        for (int d4 = 0; d4 < 16; d4++) {
            float w0 = w2t[(4 * d4 + 0) * 128 + c];
            float w1v = w2t[(4 * d4 + 1) * 128 + c];
            float w2v = w2t[(4 * d4 + 2) * 128 + c];
            float w3 = w2t[(4 * d4 + 3) * 128 + c];
#pragma unroll
            for (int j = 0; j < 16; j++) {
                const float4 p = *(const float4*)&f1[(kg + 2 * j) * 64 + 4 * d4];
                acc[j] = fmaf(p.x, w0, acc[j]);
                acc[j] = fmaf(p.y, w1v, acc[j]);
                acc[j] = fmaf(p.z, w2v, acc[j]);
                acc[j] = fmaf(p.w, w3, acc[j]);
            }
        }
#pragma unroll
        for (int j = 0; j < 16; j++)
            f2[(kg + 2 * j) * 128 + c] = fmaxf(fmaf(acc[j], a2, cc2), 0.f);
    }
    __syncthreads();
    {
        int cc = t & 127, wh = t >> 7;
        float acc[8];
#pragma unroll
        for (int i = 0; i < 8; i++) acc[i] = 0.f;
        for (int k = 0; k < KK; k++) {
            float fv = f2[k * 128 + cc];
            const float4 wa = *(const float4*)&wg[k * 16 + 8 * wh];
            const float4 wb = *(const float4*)&wg[k * 16 + 8 * wh + 4];
            acc[0] = fmaf(fv, wa.x, acc[0]);
            acc[1] = fmaf(fv, wa.y, acc[1]);
            acc[2] = fmaf(fv, wa.z, acc[2]);
            acc[3] = fmaf(fv, wa.w, acc[3]);
            acc[4] = fmaf(fv, wb.x, acc[4]);
            acc[5] = fmaf(fv, wb.y, acc[5]);
            acc[6] = fmaf(fv, wb.z, acc[6]);
            acc[7] = fmaf(fv, wb.w, acc[7]);
        }
        *(float4*)&pts[cc * 16 + 8 * wh]     = *(float4*)&acc[0];
        *(float4*)&pts[cc * 16 + 8 * wh + 4] = *(float4*)&acc[4];
    }
    __syncthreads();
#pragma unroll
    for (int i = 0; i < 8; i++)
        featsF[(size_t)blk * 2048 + i * 256 + t] = sm[i * 256 + t];
}

// ------------------------------------------------------------------
// linear_mm16: Y = feats . linB^T + lin_b via MFMA hi/lo bf16 split.
// ------------------------------------------------------------------
__global__ __launch_bounds__(256) void linear_mm16(const float* __restrict__ featsF,
                                                   const __hip_bfloat16* __restrict__ linB,
                                                   const float* __restrict__ lin_b,
                                                   float* __restrict__ stats,
                                                   float* __restrict__ ypre) {
    __shared__ __align__(16) unsigned short Ah[2][16 * 72];
    __shared__ __align__(16) unsigned short Al[2][16 * 72];
    __shared__ __align__(16) unsigned short Bsm[2][128 * 72];
    int t = threadIdx.x;
    int q0 = blockIdx.x * 16;
    int slot = blockIdx.x & (N_SLOTS - 1);
    int qa = t >> 4, pa = t & 15;
    int ob = t >> 1, pb = t & 1;
    int lane = t & 63, w = t >> 6;
    int lg = lane >> 4, ln = lane & 15;
    int qb_base = q0 + lg * 4;

    f32x4v acc0 = {0.f, 0.f, 0.f, 0.f};
    f32x4v acc1 = {0.f, 0.f, 0.f, 0.f};

    const uint4* gA0 = (const uint4*)(featsF + (size_t)(q0 + qa) * 2048);
    const uint4* gB0 = (const uint4*)(linB + (size_t)ob * 2048);

    uint4 ra, rb0, rb1, rb2, rb3;
    ra  = gA0[pa];
    rb0 = gB0[pb * 4 + 0];
    rb1 = gB0[pb * 4 + 1];
    rb2 = gB0[pb * 4 + 2];
    rb3 = gB0[pb * 4 + 3];

    for (int kc = 0; kc < 32; kc++) {
        int buf = kc & 1;
        {
            float f0 = __uint_as_float(ra.x), f1v = __uint_as_float(ra.y);
            float f2v = __uint_as_float(ra.z), f3 = __uint_as_float(ra.w);
            uint32 h0 = bf16rne(f0), h1 = bf16rne(f1v), h2 = bf16rne(f2v), h3 = bf16rne(f3);
            uint2 hv;
            hv.x = h0 | (h1 << 16); hv.y = h2 | (h3 << 16);
            *(uint2*)&Ah[buf][qa * 72 + pa * 4] = hv;
            uint32 l0 = bf16rne(f0 - __uint_as_float(h0 << 16));
            uint32 l1 = bf16rne(f1v - __uint_as_float(h1 << 16));
            uint32 l2 = bf16rne(f2v - __uint_as_float(h2 << 16));
            uint32 l3 = bf16rne(f3 - __uint_as_float(h3 << 16));
            uint2 lv;
            lv.x = l0 | (l1 << 16); lv.y = l2 | (l3 << 16);
            *(uint2*)&Al[buf][qa * 72 + pa * 4] = lv;
            *(uint4*)&Bsm[buf][ob * 72 + pb * 32 + 0]  = rb0;
            *(uint4*)&Bsm[buf][ob * 72 + pb * 32 + 8]  = rb1;
            *(uint4*)&Bsm[buf][ob * 72 + pb * 32 + 16] = rb2;
            *(uint4*)&Bsm[buf][ob * 72 + pb * 32 + 24] = rb3;
        }
        __syncthreads();
        if (kc + 1 < 32) {
            ra  = gA0[(kc + 1) * 16 + pa];
            rb0 = gB0[(kc + 1) * 8 + pb * 4 + 0];
            rb1 = gB0[(kc + 1) * 8 + pb * 4 + 1];
            rb2 = gB0[(kc + 1) * 8 + pb * 4 + 2];
            rb3 = gB0[(kc + 1) * 8 + pb * 4 + 3];
        }
#pragma unroll
        for (int s = 0; s < 2; s++) {
            int ko = s * 32 + lg * 8;
            bf16x8 ah = *(const bf16x8*)&Ah[buf][ln * 72 + ko];
            bf16x8 al = *(const bf16x8*)&Al[buf][ln * 72 + ko];
            bf16x8 b0 = *(const bf16x8*)&Bsm[buf][(w * 32 + 0  + ln) * 72 + ko];
            bf16x8 b1 = *(const bf16x8*)&Bsm[buf][(w * 32 + 16 + ln) * 72 + ko];
            acc0 = __builtin_amdgcn_mfma_f32_16x16x32_bf16(ah, b0, acc0, 0, 0, 0);
            acc0 = __builtin_amdgcn_mfma_f32_16x16x32_bf16(al, b0, acc0, 0, 0, 0);
            acc1 = __builtin_amdgcn_mfma_f32_16x16x32_bf16(ah, b1, acc1, 0, 0, 0);
            acc1 = __builtin_amdgcn_mfma_f32_16x16x32_bf16(al, b1, acc1, 0, 0, 0);
        }
    }
    {
        int o0 = w * 32 + 0  + ln;
        int o1 = w * 32 + 16 + ln;
        float lb0 = lin_b[o0], lb1 = lin_b[o1];
        float s1a = 0.f, s2a = 0.f, s1b = 0.f, s2b = 0.f;
#pragma unroll
        for (int r = 0; r < 4; r++) {
            size_t qrow = (size_t)(qb_base + r) * 128;
            float y0 = acc0[r] + lb0;
            float y1 = acc1[r] + lb1;
            ypre[qrow + o0] = y0;
            ypre[qrow + o1] = y1;
            s1a += y0; s2a += y0 * y0;
            s1b += y1; s2b += y1 * y1;
        }
        atomicAdd(&stats[slot * ST_STRIDE + ST_S1_Y + o0], s1a);
        atomicAdd(&stats[slot * ST_STRIDE + ST_S2_Y + o0], s2a);
        atomicAdd(&stats[slot * ST_STRIDE + ST_S1_Y + o1], s1b);
        atomicAdd(&stats[slot * ST_STRIDE + ST_S2_Y + o1], s2b);
    }
}

// ------------------------------------------------------------------
// final BN + relu + tiled transpose write to out1 [B,128,S]
// ------------------------------------------------------------------
__global__ __launch_bounds__(256) void bn_y(const float* __restrict__ ypre,
                                            const float* __restrict__ stats,
                                            const float* __restrict__ lg,
                                            const float* __restrict__ lb,
                                            float* __restrict__ out1) {
    __shared__ float tile[64 * 133];
    __shared__ float pa[128], pc[128];
    int blk = blockIdx.x;
    int b = blk >> 4;
    int s0 = (blk & 15) * 64;
    int t = threadIdx.x;
    if (t < 128) {
        float s1 = 0.f, s2 = 0.f;
        for (int s = 0; s < N_SLOTS; s++) {
            s1 += stats[s * ST_STRIDE + ST_S1_Y + t];
            s2 += stats[s * ST_STRIDE + ST_S2_Y + t];
        }
        const float inv = 1.f / (float)BS;
        float m = s1 * inv;
        float v = s2 * inv - m * m;
        float a = lg[t] * rsqrtf(v + 1e-5f);
        pa[t] = a;
        pc[t] = lb[t] - m * a;
    }
#pragma unroll
    for (int i = 0; i < 32; i++) {
        int idx = i * 256 + t;
        int s = idx >> 7, c = idx & 127;
        tile[s * 133 + c] = ypre[(((size_t)b << 10) + s0 + s) * 128 + c];
    }
    __syncthreads();
#pragma unroll
    for (int i = 0; i < 32; i++) {
        int idx = i * 256 + t;
        int c = idx >> 6, s = idx & 63;
        float v = tile[s * 133 + c];
        out1[((size_t)b * 128 + c) * 1024 + s0 + s] =
            fmaxf(fmaf(v, pa[c], pc[c]), 0.f);
    }
}

// ------------------------------------------------------------------
extern "C" void kernel_launch(void* const* d_in, const int* in_sizes, int n_in,
                              void* d_out, int out_size, void* d_ws, size_t ws_size,
                              hipStream_t stream) {
    const float* xyz    = (const float*)d_in[0];
    const float* points = (const float*)d_in[1];
    const float* c1_w = (const float*)d_in[2];
    const float* c1_b = (const float*)d_in[3];
    const float* g1   = (const float*)d_in[4];
    const float* b1   = (const float*)d_in[5];
    const float* c2_w = (const float*)d_in[6];
    const float* c2_b = (const float*)d_in[7];
    const float* g2   = (const float*)d_in[8];
    const float* b2   = (const float*)d_in[9];
    const float* w0_w = (const float*)d_in[10];
    const float* w0_b = (const float*)d_in[11];
    const float* w0_g = (const float*)d_in[12];
    const float* w0_be= (const float*)d_in[13];
    const float* w1_w = (const float*)d_in[14];
    const float* w1_b = (const float*)d_in[15];
    const float* w1_g = (const float*)d_in[16];
    const float* w1_be= (const float*)d_in[17];
    const float* w2_w = (const float*)d_in[18];
    const float* w2_b = (const float*)d_in[19];
    const float* w2_g = (const float*)d_in[20];
    const float* w2_be= (const float*)d_in[21];
    const float* lin_w= (const float*)d_in[22];
    const float* lin_b= (const float*)d_in[23];
    const float* lg   = (const float*)d_in[24];
    const float* lb   = (const float*)d_in[25];

    float* out0 = (float*)d_out;
    float* out1 = out0 + (size_t)BB * 3 * SS;

    char* wsb = (char*)d_ws;
    int*   nidx    = (int*)(wsb + 0);                         // 1,048,576
    float* offs    = (float*)(wsb + 1048576);                 // 3,145,728
    float* new_xyz = (float*)(wsb + 4194304);                 // 98,304
    float* ypre    = (float*)(wsb + 4292608);                 // 4,194,304
    __hip_bfloat16* ptsT = (__hip_bfloat16*)(wsb + 8486912);  // 4,194,304
    float* w1t     = (float*)(wsb + 12681216);                // 16,384 (tier2: packed bf16 hi/lo)
    float* w2t     = (float*)(wsb + 12697600);                // 32,768 (tier2: packed bf16 hi/lo)
    __hip_bfloat16* linB = (__hip_bfloat16*)(wsb + 12730368); // 524,288
    float* stats   = (float*)(wsb + 13254656);                // 180,224
    float* params  = (float*)(wsb + 13434880);                // 2,816 (floats [448,704) unused)
    int*   progress= (int*)(wsb + 13436672);                  // 64 B inside unused params tail
    float* featsF  = (float*)(wsb + 13437696);                // 67,108,864
    float* f1pre   = featsF;                                  // alias: f1pre dead before feats written
    float* f2pre   = (float*)(wsb + 80546560);                // 134,217,728 (tier-2 only)

    const size_t NEED1 = 13437696ull + 67108864ull;               // 80,546,560
    const size_t NEED2 = 80546560ull + 134217728ull;              // 214,764,288
    const int tier = (ws_size >= NEED2) ? 2 : (ws_size >= NEED1) ? 1 : 0;

    hipMemsetAsync(stats, 0, N_SLOTS * ST_STRIDE * sizeof(float), stream);
    hipMemsetAsync(progress, 0, 64, stream);

    // prep + FPS + streaming kNN; 82KB LDS => 1 block/CU (exclusive FPS CUs)
    prep_fps_knn<<<3640, 256, 0, stream>>>(points, ptsT, c1_w, c2_w, lin_w, w1t, w2t,
                                           linB, xyz, new_xyz, out0,
                                           progress, nidx, offs,
                                           tier == 2 ? 1 : 0);

    if (tier == 2) {
        pass_a2<<<BS, 256, 0, stream>>>(ptsT, nidx, offs, (const unsigned short*)w1t,
                                        c1_b, w0_w, w0_b, stats, f1pre);
    } else {
        pass_a<<<BS, 256, 0, stream>>>(ptsT, nidx, offs, w1t, c1_b, w0_w, w0_b, stats);
    }
    finalize_two<<<2, 128, 0, stream>>>(stats, params,
                                        g1, b1, ST_S1_C1, ST_S2_C1, PA_A_C1, PA_C_C1, 64, 1.f / BSK,
                                        w0_g, w0_be, ST_S1_W0, ST_S2_W0, PA_A_W0, PA_C_W0, 8, 1.f / BSK);

    if (tier == 2) {
        pass_b2<<<BS, 256, 0, stream>>>(f1pre, offs, (const unsigned short*)w2t, c2_b,
                                        w0_w, w0_b, w1_w, w1_b, params, stats, f2pre);
    } else {
        pass_b<<<BS, 256, 0, stream>>>(ptsT, nidx, offs, w1t, c1_b, w2t, c2_b,
                                       w0_w, w0_b, w1_w, w1_b, params, stats);
    }
    finalize_two<<<2, 128, 0, stream>>>(stats, params,
                                        g2, b2, ST_S1_C2, ST_S2_C2, PA_A_C2, PA_C_C2, 128, 1.f / BSK,
                                        w1_g, w1_be, ST_S1_W1, ST_S2_W1, PA_A_W1, PA_C_W1, 8, 1.f / BSK);

    pass_w2<<<BSK / 256, 256, 0, stream>>>(offs, w0_w, w0_b, w1_w, w1_b, w2_w, w2_b,
                                           params, stats);
    finalize_bn<<<1, 128, 0, stream>>>(stats, params, w2_g, w2_be,
                                       ST_S1_W2, ST_S2_W2, PA_A_W2, PA_C_W2, 16, 1.f / BSK);

    if (tier == 2) {
        tail_nl2<<<BS, 256, 0, stream>>>(f2pre, offs, w0_w, w0_b, w1_w, w1_b,
                                         w2_w, w2_b, params, featsF);
        linear_mm16<<<BS / 16, 256, 0, stream>>>(featsF, linB, lin_b, stats, ypre);
    } else {
        fused_tail_nl<<<BS, 256, 0, stream>>>(ptsT, nidx, offs, w1t, c1_b, w2t, c2_b,
                                              w0_w, w0_b, w1_w, w1_b, w2_w, w2_b,
                                              params, featsF);
        linear_mm16<<<BS / 16, 256, 0, stream>>>(featsF, linB, lin_b, stats, ypre);
    }

    bn_y<<<BB * 16, 256, 0, stream>>>(ypre, stats, lg, lb, out1);
}